// Round 2
// baseline (3824.153 us; speedup 1.0000x reference)
//
#include <hip/hip_runtime.h>
#include <hip/hip_bf16.h>
#include <math.h>

// Problem constants (fixed by setup_inputs)
static constexpr int NN   = 30000;   // nodes
static constexpr int EE   = 240000;  // edges (before self loops)
static constexpr int ET   = EE + NN; // edges incl self loops
static constexpr int BB   = 64;      // graphs
static constexpr int HH   = 10;      // heads
static constexpr int CC   = 78;      // per-head dim
static constexpr int DD   = HH * CC; // 780
static constexpr int SEQ  = 1000;
static constexpr int EMB  = 128;
static constexpr int LH   = 64;
static constexpr int COMBD = 2 * DD + 128; // 1688

// ---------------- tiled f32 GEMM: C[M,N] = A[M,K] @ B[K,N] ----------------
#define TM 128
#define TN 128
#define TKK 16
__global__ __launch_bounds__(256) void gemm_tiled(const float* __restrict__ A,
                                                  const float* __restrict__ B,
                                                  float* __restrict__ C,
                                                  int M, int N, int K) {
    __shared__ float As[TKK][TM + 4];
    __shared__ float Bs[TKK][TN];
    int tid = threadIdx.x;
    int bm = blockIdx.y * TM, bn = blockIdx.x * TN;
    int trow = tid >> 4, tcol = tid & 15;
    float acc[8][8] = {};
    for (int k0 = 0; k0 < K; k0 += TKK) {
#pragma unroll
        for (int l = 0; l < 8; ++l) {
            int idx = tid + l * 256;
            int r = idx >> 4, kk = idx & 15;
            int gr = bm + r, gk = k0 + kk;
            As[kk][r] = (gr < M && gk < K) ? A[(size_t)gr * K + gk] : 0.f;
        }
#pragma unroll
        for (int l = 0; l < 8; ++l) {
            int idx = tid + l * 256;
            int kk = idx >> 7, c = idx & 127;
            int gk = k0 + kk, gc = bn + c;
            Bs[kk][c] = (gk < K && gc < N) ? B[(size_t)gk * N + gc] : 0.f;
        }
        __syncthreads();
#pragma unroll
        for (int k = 0; k < TKK; ++k) {
            float a[8], b[8];
#pragma unroll
            for (int i = 0; i < 8; ++i) a[i] = As[k][trow * 8 + i];
#pragma unroll
            for (int j = 0; j < 8; ++j) b[j] = Bs[k][tcol * 8 + j];
#pragma unroll
            for (int i = 0; i < 8; ++i)
#pragma unroll
                for (int j = 0; j < 8; ++j) acc[i][j] += a[i] * b[j];
        }
        __syncthreads();
    }
#pragma unroll
    for (int i = 0; i < 8; ++i) {
        int r = bm + trow * 8 + i;
        if (r >= M) break;
#pragma unroll
        for (int j = 0; j < 8; ++j) {
            int c = bn + tcol * 8 + j;
            if (c < N) C[(size_t)r * N + c] = acc[i][j];
        }
    }
}

// ------------- small-M GEMM, thread per output: C = act(A@B + bias) -------------
template <int ACT>
__global__ void gemm_rowpar(const float* __restrict__ A, const float* __restrict__ B,
                            const float* __restrict__ bias, float* __restrict__ C,
                            int M, int N, int K, int ldc) {
    int idx = blockIdx.x * blockDim.x + threadIdx.x;
    if (idx >= M * N) return;
    int col = idx % N, row = idx / N;
    const float* a = A + (size_t)row * K;
    float acc = bias ? bias[col] : 0.f;
    int k = 0;
    for (; k + 3 < K; k += 4) {
        acc += a[k] * B[(size_t)k * N + col];
        acc += a[k + 1] * B[(size_t)(k + 1) * N + col];
        acc += a[k + 2] * B[(size_t)(k + 2) * N + col];
        acc += a[k + 3] * B[(size_t)(k + 3) * N + col];
    }
    for (; k < K; ++k) acc += a[k] * B[(size_t)k * N + col];
    if (ACT == 1) acc = fmaxf(acc, 0.f);
    C[(size_t)row * ldc + col] = acc;
}

// ---------------- CSR construction ----------------
__global__ void deg_count(const int* __restrict__ ei, int* __restrict__ deg) {
    int e = blockIdx.x * blockDim.x + threadIdx.x;
    if (e >= ET) return;
    int d = (e < EE) ? ei[EE + e] : (e - EE);
    atomicAdd(&deg[d], 1);
}

__global__ __launch_bounds__(1024) void scan_kernel(const int* __restrict__ deg,
                                                    int* __restrict__ offs) {
    __shared__ int lds[1024];
    int tid = threadIdx.x;
    const int chunk = (NN + 1023) / 1024;
    int base = tid * chunk;
    int s = 0;
    for (int i = 0; i < chunk; ++i) {
        int idx = base + i;
        if (idx < NN) s += deg[idx];
    }
    lds[tid] = s;
    __syncthreads();
    for (int d = 1; d < 1024; d <<= 1) {
        int v = (tid >= d) ? lds[tid - d] : 0;
        __syncthreads();
        lds[tid] += v;
        __syncthreads();
    }
    int run = (tid == 0) ? 0 : lds[tid - 1];
    for (int i = 0; i < chunk; ++i) {
        int idx = base + i;
        if (idx < NN) { offs[idx] = run; run += deg[idx]; }
    }
    if (tid == 1023) offs[NN] = lds[1023];
}

__global__ void csr_fill(const int* __restrict__ ei, const int* __restrict__ offs,
                         int* __restrict__ cursor, int* __restrict__ csr_src,
                         int* __restrict__ csr_dst) {
    int e = blockIdx.x * blockDim.x + threadIdx.x;
    if (e >= ET) return;
    int s = (e < EE) ? ei[e] : (e - EE);
    int d = (e < EE) ? ei[EE + e] : (e - EE);
    int pos = atomicAdd(&cursor[d], 1);
    int slot = offs[d] + pos;
    csr_src[slot] = s;
    csr_dst[slot] = d;
}

__global__ void dinv_kernel(const int* __restrict__ deg, float* __restrict__ dinv) {
    int n = blockIdx.x * blockDim.x + threadIdx.x;
    if (n >= NN) return;
    float dg = (float)deg[n];
    dinv[n] = (dg > 0.f) ? 1.f / sqrtf(dg) : 0.f;
}

// ---------------- GATv2 ----------------
__global__ void gat_logits(const float* __restrict__ xl, const float* __restrict__ xr,
                           const float* __restrict__ att, const int* __restrict__ csr_src,
                           const int* __restrict__ csr_dst, float* __restrict__ logit) {
    int idx = blockIdx.x * blockDim.x + threadIdx.x;
    if (idx >= ET * HH) return;
    int i = idx / HH, h = idx % HH;
    int s = csr_src[i], d = csr_dst[i];
    const float* pl = xl + (size_t)s * DD + h * CC;
    const float* pr = xr + (size_t)d * DD + h * CC;
    const float* pa = att + h * CC;
    float acc = 0.f;
    for (int c = 0; c < CC; ++c) {
        float v = pl[c] + pr[c];
        v = (v > 0.f) ? v : 0.2f * v;
        acc += pa[c] * v;
    }
    logit[idx] = acc;
}

__global__ void gat_softmax(const int* __restrict__ offs, float* __restrict__ logit) {
    int idx = blockIdx.x * blockDim.x + threadIdx.x;
    if (idx >= NN * HH) return;
    int n = idx / HH, h = idx % HH;
    int i0 = offs[n], i1 = offs[n + 1];
    float m = -1e30f;
    for (int i = i0; i < i1; ++i) m = fmaxf(m, logit[i * HH + h]);
    float den = 0.f;
    for (int i = i0; i < i1; ++i) {
        float e = expf(logit[i * HH + h] - m);
        logit[i * HH + h] = e;
        den += e;
    }
    float inv = 1.f / den;
    for (int i = i0; i < i1; ++i) logit[i * HH + h] *= inv;
}

__global__ __launch_bounds__(256) void gat_aggregate(const int* __restrict__ offs,
                                                     const int* __restrict__ csr_src,
                                                     const float* __restrict__ alpha,
                                                     const float* __restrict__ xl,
                                                     const float* __restrict__ gat_b,
                                                     float* __restrict__ hout) {
    int n = blockIdx.x;
    int i0 = offs[n], i1 = offs[n + 1];
    for (int d = threadIdx.x; d < DD; d += 256) {
        int h = d / CC;
        float acc = 0.f;
        for (int i = i0; i < i1; ++i)
            acc += alpha[i * HH + h] * xl[(size_t)csr_src[i] * DD + d];
        acc += gat_b[d];
        hout[(size_t)n * DD + d] = (acc > 0.f) ? acc : expf(acc) - 1.f;
    }
}

// ---------------- GCN aggregation ----------------
__global__ __launch_bounds__(256) void gcn_aggregate(const int* __restrict__ offs,
                                                     const int* __restrict__ csr_src,
                                                     const float* __restrict__ dinv,
                                                     const float* __restrict__ hw,
                                                     const float* __restrict__ gcn_b,
                                                     float* __restrict__ g) {
    int n = blockIdx.x;
    float din = dinv[n];
    int i0 = offs[n], i1 = offs[n + 1];
    for (int d = threadIdx.x; d < DD; d += 256) {
        float acc = 0.f;
        for (int i = i0; i < i1; ++i) {
            int s = csr_src[i];
            acc += dinv[s] * din * hw[(size_t)s * DD + d];
        }
        acc += gcn_b[d];
        g[(size_t)n * DD + d] = fmaxf(acc, 0.f);
    }
}

// ---------------- pooling ----------------
__global__ void graph_ranges(const int* __restrict__ batch, int* __restrict__ gstart,
                             int* __restrict__ gend) {
    int n = blockIdx.x * blockDim.x + threadIdx.x;
    if (n >= NN) return;
    int b = batch[n];
    if (n == 0 || batch[n - 1] != b) gstart[b] = n;
    if (n == NN - 1 || batch[n + 1] != b) gend[b] = n + 1;
}

__global__ __launch_bounds__(256) void pool_kernel(const float* __restrict__ g,
                                                   const int* __restrict__ gstart,
                                                   const int* __restrict__ gend,
                                                   float* __restrict__ comb) {
    int b = blockIdx.x;
    int s = gstart[b], e = gend[b];
    float cnt = fmaxf((float)(e - s), 1.f);
    for (int d = threadIdx.x; d < DD; d += 256) {
        float mx = -1e30f, sm = 0.f;
        for (int n = s; n < e; ++n) {
            float v = g[(size_t)n * DD + d];
            mx = fmaxf(mx, v);
            sm += v;
        }
        comb[(size_t)b * COMBD + d] = mx;
        comb[(size_t)b * COMBD + DD + d] = sm / cnt;
    }
}

// ---------------- protein branch ----------------
__global__ void proj26_kernel(const float* __restrict__ emb,
                              const float* __restrict__ Wih_f, const float* __restrict__ bih_f,
                              const float* __restrict__ bhh_f,
                              const float* __restrict__ Wih_b, const float* __restrict__ bih_b,
                              const float* __restrict__ bhh_b, float* __restrict__ proj) {
    int dir = blockIdx.x, row = blockIdx.y, j = threadIdx.x;
    const float* W = dir ? Wih_b : Wih_f;
    const float* b1 = dir ? bih_b : bih_f;
    const float* b2 = dir ? bhh_b : bhh_f;
    float acc = b1[j] + b2[j];
    const float* e = emb + row * EMB;
    const float* w = W + j * EMB;
    for (int k = 0; k < EMB; ++k) acc += e[k] * w[k];
    proj[(dir * 26 + row) * 256 + j] = acc;
}

__global__ __launch_bounds__(256) void lstm_kernel(const int* __restrict__ target,
                                                   const float* __restrict__ proj26,
                                                   const float* __restrict__ Whh_f,
                                                   const float* __restrict__ Whh_b,
                                                   float* __restrict__ hcat) {
    int n = blockIdx.x;      // 0..999 (sequence position == LSTM batch element)
    int dir = blockIdx.y;    // 0 fwd, 1 bwd
    int tid = threadIdx.x;   // 0..255 (gate unit)
    const float* Whh = dir ? Whh_b : Whh_f;
    const float* proj = proj26 + dir * 26 * 256;
    float w[LH];
#pragma unroll
    for (int u4 = 0; u4 < LH / 4; ++u4) {
        float4 v = *reinterpret_cast<const float4*>(Whh + tid * LH + u4 * 4);
        w[u4 * 4 + 0] = v.x; w[u4 * 4 + 1] = v.y;
        w[u4 * 4 + 2] = v.z; w[u4 * 4 + 3] = v.w;
    }
    __shared__ float h_lds[LH];
    __shared__ float c_lds[LH];
    __shared__ float z_lds[256];
    if (tid < LH) { h_lds[tid] = 0.f; c_lds[tid] = 0.f; }
    __syncthreads();
    for (int s = 0; s < BB; ++s) {
        int t = dir ? (BB - 1 - s) : s;
        int tgt = target[t * SEQ + n];
        float a0 = 0.f, a1 = 0.f, a2 = 0.f, a3 = 0.f;
#pragma unroll
        for (int u = 0; u < LH; u += 4) {
            a0 += w[u] * h_lds[u];
            a1 += w[u + 1] * h_lds[u + 1];
            a2 += w[u + 2] * h_lds[u + 2];
            a3 += w[u + 3] * h_lds[u + 3];
        }
        z_lds[tid] = proj[tgt * 256 + tid] + a0 + a1 + a2 + a3;
        __syncthreads();
        if (tid < LH) {
            float ig = 1.f / (1.f + expf(-z_lds[tid]));
            float fg = 1.f / (1.f + expf(-z_lds[LH + tid]));
            float gg = tanhf(z_lds[2 * LH + tid]);
            float og = 1.f / (1.f + expf(-z_lds[3 * LH + tid]));
            float c = fg * c_lds[tid] + ig * gg;
            float h = og * tanhf(c);
            c_lds[tid] = c;
            h_lds[tid] = h;
            hcat[((size_t)t * SEQ + n) * 128 + dir * LH + tid] = h;
        }
        __syncthreads();
    }
}

__global__ void conv_kernel(const float* __restrict__ hcat, const float* __restrict__ conv_w,
                            const float* __restrict__ conv_b, float* __restrict__ convout) {
    int b = blockIdx.x;   // 64
    int og = blockIdx.y;  // 8 groups of 4 out channels
    int p = threadIdx.x;  // 0..127
    if (p >= 121) return;
    float acc[4] = {0.f, 0.f, 0.f, 0.f};
    for (int i = 0; i < SEQ; ++i) {
        const float* hrow = hcat + ((size_t)b * SEQ + i) * 128;
        float x[8];
#pragma unroll
        for (int k = 0; k < 8; ++k) x[k] = hrow[p + k];
#pragma unroll
        for (int oo = 0; oo < 4; ++oo) {
            const float* wr = conv_w + ((size_t)(og * 4 + oo) * SEQ + i) * 8;
#pragma unroll
            for (int k = 0; k < 8; ++k) acc[oo] += x[k] * wr[k];
        }
    }
#pragma unroll
    for (int oo = 0; oo < 4; ++oo) {
        int o = og * 4 + oo;
        convout[(size_t)b * 3872 + o * 121 + p] = acc[oo] + conv_b[o];
    }
}

// ---------------- launcher ----------------
extern "C" void kernel_launch(void* const* d_in, const int* in_sizes, int n_in,
                              void* d_out, int out_size, void* d_ws, size_t ws_size,
                              hipStream_t stream) {
    const float* x      = (const float*)d_in[0];
    const int*   ei     = (const int*)d_in[1];
    const int*   batch  = (const int*)d_in[2];
    const int*   target = (const int*)d_in[3];
    const float* Wl     = (const float*)d_in[4];
    const float* Wr     = (const float*)d_in[5];
    const float* att    = (const float*)d_in[6];
    const float* gat_b  = (const float*)d_in[7];
    const float* gcn_w  = (const float*)d_in[8];
    const float* gcn_b  = (const float*)d_in[9];
    const float* emb    = (const float*)d_in[10];
    const float* Wih_f  = (const float*)d_in[11];
    const float* Whh_f  = (const float*)d_in[12];
    const float* bih_f  = (const float*)d_in[13];
    const float* bhh_f  = (const float*)d_in[14];
    const float* Wih_b  = (const float*)d_in[15];
    const float* Whh_b  = (const float*)d_in[16];
    const float* bih_b  = (const float*)d_in[17];
    const float* bhh_b  = (const float*)d_in[18];
    const float* conv_w = (const float*)d_in[19];
    const float* conv_b = (const float*)d_in[20];
    const float* fcp_w  = (const float*)d_in[21];
    const float* fcp_b  = (const float*)d_in[22];
    const float* fc1_w  = (const float*)d_in[23];
    const float* fc1_b  = (const float*)d_in[24];
    const float* fc2_w  = (const float*)d_in[25];
    const float* fc2_b  = (const float*)d_in[26];
    const float* out_w  = (const float*)d_in[27];
    const float* out_b  = (const float*)d_in[28];
    float* out = (float*)d_out;
    (void)n_in; (void)in_sizes; (void)out_size;

    // ---------- workspace layout (phase-union to minimize footprint) ----------
    char* ws = (char*)d_ws;
    size_t o = 0;
    auto alloc = [&](size_t bytes) {
        char* p = ws + o;
        o = (o + bytes + 255) & ~(size_t)255;
        return p;
    };
    constexpr size_t BIG = (size_t)NN * DD * 4; // 93.6 MB
    // Union region: protein phase {hcat, proj26, convout} then graph phase {A_buf, B_buf}
    char* region = (char*)alloc(2 * BIG + 256);
    float* A_buf = (float*)region;                      // xl -> hw
    float* B_buf = (float*)(region + BIG);              // xr -> h -> g
    float* hcat    = (float*)region;                                     // 32.8 MB
    float* proj26  = (float*)(region + (size_t)BB * SEQ * 128 * 4 + 256); // 53 KB
    float* convout = (float*)((char*)proj26 + 2 * 26 * 256 * 4 + 256);    // 1 MB
    // Persistent small buffers
    float* logit    = (float*)alloc((size_t)ET * HH * 4); // logits -> alpha in place
    int*   csr_src  = (int*)alloc((size_t)ET * 4);
    int*   csr_dst  = (int*)alloc((size_t)ET * 4);
    int*   deg      = (int*)alloc((size_t)NN * 4);
    int*   cursor   = (int*)alloc((size_t)NN * 4);
    int*   offs     = (int*)alloc((size_t)(NN + 1) * 4);
    float* dinv     = (float*)alloc((size_t)NN * 4);
    int*   gstart   = (int*)alloc(64 * 4);
    int*   gend     = (int*)alloc(64 * 4);
    float* comb     = (float*)alloc((size_t)BB * COMBD * 4);
    float* h1       = (float*)alloc((size_t)BB * 1024 * 4);
    float* h2       = (float*)alloc((size_t)BB * 512 * 4);
    if (o > ws_size) return;  // diagnostic: insufficient workspace -> no launches, no fault

    // zero scratch that is accumulated into (ws is NOT re-poisoned between replays)
    hipMemsetAsync(deg, 0, (size_t)NN * 4, stream);
    hipMemsetAsync(cursor, 0, (size_t)NN * 4, stream);
    hipMemsetAsync(gstart, 0, 64 * 4, stream);
    hipMemsetAsync(gend, 0, 64 * 4, stream);

    // ---------- protein branch (first: its buffers alias the graph region) ----------
    {
        dim3 grid(2, 26);
        proj26_kernel<<<grid, 256, 0, stream>>>(emb, Wih_f, bih_f, bhh_f, Wih_b, bih_b, bhh_b, proj26);
    }
    {
        dim3 grid(SEQ, 2);
        lstm_kernel<<<grid, 256, 0, stream>>>(target, proj26, Whh_f, Whh_b, hcat);
    }
    {
        dim3 grid(BB, 8);
        conv_kernel<<<grid, 128, 0, stream>>>(hcat, conv_w, conv_b, convout);
    }
    gemm_rowpar<0><<<(BB * 128 + 255) / 256, 256, 0, stream>>>(convout, fcp_w, fcp_b,
                                                               comb + 2 * DD, BB, 128, 3872, COMBD);

    // ---------- graph branch ----------
    // xl = x @ Wl (A_buf), xr = x @ Wr (B_buf)
    {
        dim3 grid((DD + TN - 1) / TN, (NN + TM - 1) / TM);
        gemm_tiled<<<grid, 256, 0, stream>>>(x, Wl, A_buf, NN, DD, CC);
        gemm_tiled<<<grid, 256, 0, stream>>>(x, Wr, B_buf, NN, DD, CC);
    }
    // CSR
    deg_count<<<(ET + 255) / 256, 256, 0, stream>>>(ei, deg);
    scan_kernel<<<1, 1024, 0, stream>>>(deg, offs);
    csr_fill<<<(ET + 255) / 256, 256, 0, stream>>>(ei, offs, cursor, csr_src, csr_dst);
    dinv_kernel<<<(NN + 255) / 256, 256, 0, stream>>>(deg, dinv);
    // GATv2: logits read A(xl) + B(xr); aggregate reads A, writes B (h)
    gat_logits<<<(ET * HH + 255) / 256, 256, 0, stream>>>(A_buf, B_buf, att, csr_src, csr_dst, logit);
    gat_softmax<<<(NN * HH + 255) / 256, 256, 0, stream>>>(offs, logit);
    gat_aggregate<<<NN, 256, 0, stream>>>(offs, csr_src, logit, A_buf, gat_b, B_buf);
    // GCN: hw = h @ gcn_w  (reads B, writes A); aggregate reads A, writes B (g)
    {
        dim3 grid((DD + TN - 1) / TN, (NN + TM - 1) / TM);
        gemm_tiled<<<grid, 256, 0, stream>>>(B_buf, gcn_w, A_buf, NN, DD, DD);
    }
    gcn_aggregate<<<NN, 256, 0, stream>>>(offs, csr_src, dinv, A_buf, gcn_b, B_buf);
    // pooling -> comb[:, 0:1560]
    graph_ranges<<<(NN + 255) / 256, 256, 0, stream>>>(batch, gstart, gend);
    pool_kernel<<<BB, 256, 0, stream>>>(B_buf, gstart, gend, comb);

    // ---------- combined head ----------
    gemm_rowpar<1><<<(BB * 1024 + 255) / 256, 256, 0, stream>>>(comb, fc1_w, fc1_b, h1,
                                                                BB, 1024, COMBD, 1024);
    gemm_rowpar<1><<<(BB * 512 + 255) / 256, 256, 0, stream>>>(h1, fc2_w, fc2_b, h2,
                                                               BB, 512, 1024, 512);
    gemm_rowpar<0><<<1, 256, 0, stream>>>(h2, out_w, out_b, out, BB, 1, 512, 1);
}

// Round 3
// 2471.108 us; speedup vs baseline: 1.5475x; 1.5475x over previous
//
#include <hip/hip_runtime.h>
#include <hip/hip_bf16.h>
#include <math.h>

// Problem constants (fixed by setup_inputs)
static constexpr int NN   = 30000;   // nodes
static constexpr int EE   = 240000;  // edges (before self loops)
static constexpr int ET   = EE + NN; // edges incl self loops
static constexpr int BB   = 64;      // graphs
static constexpr int HH   = 10;      // heads
static constexpr int CC   = 78;      // per-head dim
static constexpr int DD   = HH * CC; // 780
static constexpr int SEQ  = 1000;
static constexpr int EMB  = 128;
static constexpr int LH   = 64;
static constexpr int COMBD = 2 * DD + 128; // 1688

typedef __attribute__((ext_vector_type(8))) short short8;
typedef __attribute__((ext_vector_type(4))) float f32x4;

// ---------------- bf16 MFMA GEMM: C[M,N] = A[M,K] @ Bt[N,K]^T ----------------
// A, Bt row-major bf16; C f32. K must be even (78 / 780 here). 128x128 tile,
// BK=32, 4 waves (2x2), each wave 64x64 via 4x4 fragments of 16x16x32.
// LDS row stride 40 shorts (80 B) -> row-to-row bank stride 20 -> <=2-way conflict (free).
__global__ __launch_bounds__(256) void gemm_bf16_mfma(const __hip_bfloat16* __restrict__ A,
                                                      const __hip_bfloat16* __restrict__ Bt,
                                                      float* __restrict__ C,
                                                      int M, int N, int K) {
    constexpr int LDS_S = 40;
    __shared__ unsigned short As[128 * LDS_S];
    __shared__ unsigned short Bs[128 * LDS_S];
    const int tid  = threadIdx.x;
    const int lane = tid & 63, wid = tid >> 6;
    const int wr = wid >> 1, wc = wid & 1;
    const int l15 = lane & 15, l4 = lane >> 4;
    const int bm = blockIdx.y * 128, bn = blockIdx.x * 128;
    const int tr = tid >> 2, tc = (tid & 3) * 8;

    const unsigned short* Au = (const unsigned short*)A;
    const unsigned short* Bu = (const unsigned short*)Bt;

    f32x4 acc[4][4];
#pragma unroll
    for (int m = 0; m < 4; ++m)
#pragma unroll
        for (int n = 0; n < 4; ++n) acc[m][n] = (f32x4){0.f, 0.f, 0.f, 0.f};

    for (int k0 = 0; k0 < K; k0 += 32) {
#pragma unroll
        for (int half = 0; half < 2; ++half) {
            int row = tr + half * 64;
            { // A tile
                int grow = bm + row;
                short8 sv;
                if (grow < M && k0 + tc + 8 <= K) {
                    const unsigned int* p = (const unsigned int*)(Au + (size_t)grow * K + k0 + tc);
#pragma unroll
                    for (int j = 0; j < 4; ++j) {
                        unsigned int u = p[j];
                        sv[2 * j]     = (short)(u & 0xffffu);
                        sv[2 * j + 1] = (short)(u >> 16);
                    }
                } else {
#pragma unroll
                    for (int j = 0; j < 8; ++j) {
                        int gk = k0 + tc + j;
                        sv[j] = (grow < M && gk < K) ? (short)Au[(size_t)grow * K + gk] : (short)0;
                    }
                }
                *reinterpret_cast<short8*>(&As[row * LDS_S + tc]) = sv;
            }
            { // B^T tile
                int grow = bn + row;
                short8 sv;
                if (grow < N && k0 + tc + 8 <= K) {
                    const unsigned int* p = (const unsigned int*)(Bu + (size_t)grow * K + k0 + tc);
#pragma unroll
                    for (int j = 0; j < 4; ++j) {
                        unsigned int u = p[j];
                        sv[2 * j]     = (short)(u & 0xffffu);
                        sv[2 * j + 1] = (short)(u >> 16);
                    }
                } else {
#pragma unroll
                    for (int j = 0; j < 8; ++j) {
                        int gk = k0 + tc + j;
                        sv[j] = (grow < N && gk < K) ? (short)Bu[(size_t)grow * K + gk] : (short)0;
                    }
                }
                *reinterpret_cast<short8*>(&Bs[row * LDS_S + tc]) = sv;
            }
        }
        __syncthreads();
        short8 a[4], b[4];
#pragma unroll
        for (int m = 0; m < 4; ++m)
            a[m] = *reinterpret_cast<const short8*>(&As[(wr * 64 + m * 16 + l15) * LDS_S + l4 * 8]);
#pragma unroll
        for (int n = 0; n < 4; ++n)
            b[n] = *reinterpret_cast<const short8*>(&Bs[(wc * 64 + n * 16 + l15) * LDS_S + l4 * 8]);
#pragma unroll
        for (int m = 0; m < 4; ++m)
#pragma unroll
            for (int n = 0; n < 4; ++n)
                acc[m][n] = __builtin_amdgcn_mfma_f32_16x16x32_bf16(a[m], b[n], acc[m][n], 0, 0, 0);
        __syncthreads();
    }
#pragma unroll
    for (int m = 0; m < 4; ++m)
#pragma unroll
        for (int n = 0; n < 4; ++n)
#pragma unroll
            for (int r = 0; r < 4; ++r) {
                int row = bm + wr * 64 + m * 16 + l4 * 4 + r;
                int col = bn + wc * 64 + n * 16 + l15;
                if (row < M && col < N) C[(size_t)row * N + col] = acc[m][n][r];
            }
}

// ---------------- conversions ----------------
__global__ void f32_to_bf16(const float* __restrict__ in, __hip_bfloat16* __restrict__ out, int n) {
    int i = blockIdx.x * blockDim.x + threadIdx.x;
    if (i < n) out[i] = __float2bfloat16(in[i]);
}

// in[K][N] f32 -> out[N][K] bf16
__global__ void transpose_to_bf16(const float* __restrict__ in, __hip_bfloat16* __restrict__ out,
                                  int Kdim, int Ndim) {
    int idx = blockIdx.x * blockDim.x + threadIdx.x;
    if (idx >= Kdim * Ndim) return;
    int n = idx / Kdim, k = idx % Kdim;
    out[idx] = __float2bfloat16(in[(size_t)k * Ndim + n]);
}

// ------------- small-M GEMM, thread per output: C = act(A@B + bias) -------------
template <int ACT>
__global__ void gemm_rowpar(const float* __restrict__ A, const float* __restrict__ B,
                            const float* __restrict__ bias, float* __restrict__ C,
                            int M, int N, int K, int ldc) {
    int idx = blockIdx.x * blockDim.x + threadIdx.x;
    if (idx >= M * N) return;
    int col = idx % N, row = idx / N;
    const float* a = A + (size_t)row * K;
    float acc = bias ? bias[col] : 0.f;
    int k = 0;
    for (; k + 3 < K; k += 4) {
        acc += a[k] * B[(size_t)k * N + col];
        acc += a[k + 1] * B[(size_t)(k + 1) * N + col];
        acc += a[k + 2] * B[(size_t)(k + 2) * N + col];
        acc += a[k + 3] * B[(size_t)(k + 3) * N + col];
    }
    for (; k < K; ++k) acc += a[k] * B[(size_t)k * N + col];
    if (ACT == 1) acc = fmaxf(acc, 0.f);
    C[(size_t)row * ldc + col] = acc;
}

// ---------------- CSR construction ----------------
__global__ void deg_count(const int* __restrict__ ei, int* __restrict__ deg) {
    int e = blockIdx.x * blockDim.x + threadIdx.x;
    if (e >= ET) return;
    int d = (e < EE) ? ei[EE + e] : (e - EE);
    atomicAdd(&deg[d], 1);
}

__global__ __launch_bounds__(1024) void scan_kernel(const int* __restrict__ deg,
                                                    int* __restrict__ offs) {
    __shared__ int lds[1024];
    int tid = threadIdx.x;
    const int chunk = (NN + 1023) / 1024;
    int base = tid * chunk;
    int s = 0;
    for (int i = 0; i < chunk; ++i) {
        int idx = base + i;
        if (idx < NN) s += deg[idx];
    }
    lds[tid] = s;
    __syncthreads();
    for (int d = 1; d < 1024; d <<= 1) {
        int v = (tid >= d) ? lds[tid - d] : 0;
        __syncthreads();
        lds[tid] += v;
        __syncthreads();
    }
    int run = (tid == 0) ? 0 : lds[tid - 1];
    for (int i = 0; i < chunk; ++i) {
        int idx = base + i;
        if (idx < NN) { offs[idx] = run; run += deg[idx]; }
    }
    if (tid == 1023) offs[NN] = lds[1023];
}

__global__ void csr_fill(const int* __restrict__ ei, const int* __restrict__ offs,
                         int* __restrict__ cursor, int* __restrict__ csr_src,
                         int* __restrict__ csr_dst) {
    int e = blockIdx.x * blockDim.x + threadIdx.x;
    if (e >= ET) return;
    int s = (e < EE) ? ei[e] : (e - EE);
    int d = (e < EE) ? ei[EE + e] : (e - EE);
    int pos = atomicAdd(&cursor[d], 1);
    int slot = offs[d] + pos;
    csr_src[slot] = s;
    csr_dst[slot] = d;
}

__global__ void dinv_kernel(const int* __restrict__ deg, float* __restrict__ dinv) {
    int n = blockIdx.x * blockDim.x + threadIdx.x;
    if (n >= NN) return;
    float dg = (float)deg[n];
    dinv[n] = (dg > 0.f) ? 1.f / sqrtf(dg) : 0.f;
}

// ---------------- GATv2 ----------------
__global__ void gat_logits(const float* __restrict__ xl, const float* __restrict__ xr,
                           const float* __restrict__ att, const int* __restrict__ csr_src,
                           const int* __restrict__ csr_dst, float* __restrict__ logit) {
    int idx = blockIdx.x * blockDim.x + threadIdx.x;
    if (idx >= ET * HH) return;
    int i = idx / HH, h = idx % HH;
    int s = csr_src[i], d = csr_dst[i];
    const float* pl = xl + (size_t)s * DD + h * CC;
    const float* pr = xr + (size_t)d * DD + h * CC;
    const float* pa = att + h * CC;
    float acc = 0.f;
    for (int c = 0; c < CC; ++c) {
        float v = pl[c] + pr[c];
        v = (v > 0.f) ? v : 0.2f * v;
        acc += pa[c] * v;
    }
    logit[idx] = acc;
}

__global__ void gat_softmax(const int* __restrict__ offs, float* __restrict__ logit) {
    int idx = blockIdx.x * blockDim.x + threadIdx.x;
    if (idx >= NN * HH) return;
    int n = idx / HH, h = idx % HH;
    int i0 = offs[n], i1 = offs[n + 1];
    float m = -1e30f;
    for (int i = i0; i < i1; ++i) m = fmaxf(m, logit[i * HH + h]);
    float den = 0.f;
    for (int i = i0; i < i1; ++i) {
        float e = expf(logit[i * HH + h] - m);
        logit[i * HH + h] = e;
        den += e;
    }
    float inv = 1.f / den;
    for (int i = i0; i < i1; ++i) logit[i * HH + h] *= inv;
}

// writes h as bf16 (consumed by the GCN MFMA GEMM)
__global__ __launch_bounds__(256) void gat_aggregate(const int* __restrict__ offs,
                                                     const int* __restrict__ csr_src,
                                                     const float* __restrict__ alpha,
                                                     const float* __restrict__ xl,
                                                     const float* __restrict__ gat_b,
                                                     __hip_bfloat16* __restrict__ hout) {
    int n = blockIdx.x;
    int i0 = offs[n], i1 = offs[n + 1];
    for (int d = threadIdx.x; d < DD; d += 256) {
        int h = d / CC;
        float acc = 0.f;
        for (int i = i0; i < i1; ++i)
            acc += alpha[i * HH + h] * xl[(size_t)csr_src[i] * DD + d];
        acc += gat_b[d];
        float v = (acc > 0.f) ? acc : expf(acc) - 1.f;
        hout[(size_t)n * DD + d] = __float2bfloat16(v);
    }
}

// ---------------- GCN aggregation ----------------
__global__ __launch_bounds__(256) void gcn_aggregate(const int* __restrict__ offs,
                                                     const int* __restrict__ csr_src,
                                                     const float* __restrict__ dinv,
                                                     const float* __restrict__ hw,
                                                     const float* __restrict__ gcn_b,
                                                     float* __restrict__ g) {
    int n = blockIdx.x;
    float din = dinv[n];
    int i0 = offs[n], i1 = offs[n + 1];
    for (int d = threadIdx.x; d < DD; d += 256) {
        float acc = 0.f;
        for (int i = i0; i < i1; ++i) {
            int s = csr_src[i];
            acc += dinv[s] * din * hw[(size_t)s * DD + d];
        }
        acc += gcn_b[d];
        g[(size_t)n * DD + d] = fmaxf(acc, 0.f);
    }
}

// ---------------- pooling ----------------
__global__ void graph_ranges(const int* __restrict__ batch, int* __restrict__ gstart,
                             int* __restrict__ gend) {
    int n = blockIdx.x * blockDim.x + threadIdx.x;
    if (n >= NN) return;
    int b = batch[n];
    if (n == 0 || batch[n - 1] != b) gstart[b] = n;
    if (n == NN - 1 || batch[n + 1] != b) gend[b] = n + 1;
}

__global__ __launch_bounds__(256) void pool_kernel(const float* __restrict__ g,
                                                   const int* __restrict__ gstart,
                                                   const int* __restrict__ gend,
                                                   float* __restrict__ comb) {
    int b = blockIdx.x;
    int s = gstart[b], e = gend[b];
    float cnt = fmaxf((float)(e - s), 1.f);
    for (int d = threadIdx.x; d < DD; d += 256) {
        float mx = -1e30f, sm = 0.f;
        for (int n = s; n < e; ++n) {
            float v = g[(size_t)n * DD + d];
            mx = fmaxf(mx, v);
            sm += v;
        }
        comb[(size_t)b * COMBD + d] = mx;
        comb[(size_t)b * COMBD + DD + d] = sm / cnt;
    }
}

// ---------------- protein branch ----------------
__global__ void proj26_kernel(const float* __restrict__ emb,
                              const float* __restrict__ Wih_f, const float* __restrict__ bih_f,
                              const float* __restrict__ bhh_f,
                              const float* __restrict__ Wih_b, const float* __restrict__ bih_b,
                              const float* __restrict__ bhh_b, float* __restrict__ proj) {
    int dir = blockIdx.x, row = blockIdx.y, j = threadIdx.x;
    const float* W = dir ? Wih_b : Wih_f;
    const float* b1 = dir ? bih_b : bih_f;
    const float* b2 = dir ? bhh_b : bhh_f;
    float acc = b1[j] + b2[j];
    const float* e = emb + row * EMB;
    const float* w = W + j * EMB;
    for (int k = 0; k < EMB; ++k) acc += e[k] * w[k];
    proj[(dir * 26 + row) * 256 + j] = acc;
}

__global__ __launch_bounds__(256) void lstm_kernel(const int* __restrict__ target,
                                                   const float* __restrict__ proj26,
                                                   const float* __restrict__ Whh_f,
                                                   const float* __restrict__ Whh_b,
                                                   float* __restrict__ hcat) {
    int n = blockIdx.x;      // 0..999 (sequence position == LSTM batch element)
    int dir = blockIdx.y;    // 0 fwd, 1 bwd
    int tid = threadIdx.x;   // 0..255 (gate unit)
    const float* Whh = dir ? Whh_b : Whh_f;
    const float* proj = proj26 + dir * 26 * 256;
    float w[LH];
#pragma unroll
    for (int u4 = 0; u4 < LH / 4; ++u4) {
        float4 v = *reinterpret_cast<const float4*>(Whh + tid * LH + u4 * 4);
        w[u4 * 4 + 0] = v.x; w[u4 * 4 + 1] = v.y;
        w[u4 * 4 + 2] = v.z; w[u4 * 4 + 3] = v.w;
    }
    __shared__ float h_lds[LH];
    __shared__ float c_lds[LH];
    __shared__ float z_lds[256];
    if (tid < LH) { h_lds[tid] = 0.f; c_lds[tid] = 0.f; }
    __syncthreads();
    for (int s = 0; s < BB; ++s) {
        int t = dir ? (BB - 1 - s) : s;
        int tgt = target[t * SEQ + n];
        float a0 = 0.f, a1 = 0.f, a2 = 0.f, a3 = 0.f;
#pragma unroll
        for (int u = 0; u < LH; u += 4) {
            a0 += w[u] * h_lds[u];
            a1 += w[u + 1] * h_lds[u + 1];
            a2 += w[u + 2] * h_lds[u + 2];
            a3 += w[u + 3] * h_lds[u + 3];
        }
        z_lds[tid] = proj[tgt * 256 + tid] + a0 + a1 + a2 + a3;
        __syncthreads();
        if (tid < LH) {
            float ig = 1.f / (1.f + expf(-z_lds[tid]));
            float fg = 1.f / (1.f + expf(-z_lds[LH + tid]));
            float gg = tanhf(z_lds[2 * LH + tid]);
            float og = 1.f / (1.f + expf(-z_lds[3 * LH + tid]));
            float c = fg * c_lds[tid] + ig * gg;
            float h = og * tanhf(c);
            c_lds[tid] = c;
            h_lds[tid] = h;
            hcat[((size_t)t * SEQ + n) * 128 + dir * LH + tid] = h;
        }
        __syncthreads();
    }
}

__global__ void conv_kernel(const float* __restrict__ hcat, const float* __restrict__ conv_w,
                            const float* __restrict__ conv_b, float* __restrict__ convout) {
    int b = blockIdx.x;   // 64
    int og = blockIdx.y;  // 8 groups of 4 out channels
    int p = threadIdx.x;  // 0..127
    if (p >= 121) return;
    float acc[4] = {0.f, 0.f, 0.f, 0.f};
    for (int i = 0; i < SEQ; ++i) {
        const float* hrow = hcat + ((size_t)b * SEQ + i) * 128;
        float x[8];
#pragma unroll
        for (int k = 0; k < 8; ++k) x[k] = hrow[p + k];
#pragma unroll
        for (int oo = 0; oo < 4; ++oo) {
            const float* wr = conv_w + ((size_t)(og * 4 + oo) * SEQ + i) * 8;
#pragma unroll
            for (int k = 0; k < 8; ++k) acc[oo] += x[k] * wr[k];
        }
    }
#pragma unroll
    for (int oo = 0; oo < 4; ++oo) {
        int o = og * 4 + oo;
        convout[(size_t)b * 3872 + o * 121 + p] = acc[oo] + conv_b[o];
    }
}

// ---------------- launcher ----------------
extern "C" void kernel_launch(void* const* d_in, const int* in_sizes, int n_in,
                              void* d_out, int out_size, void* d_ws, size_t ws_size,
                              hipStream_t stream) {
    const float* x      = (const float*)d_in[0];
    const int*   ei     = (const int*)d_in[1];
    const int*   batch  = (const int*)d_in[2];
    const int*   target = (const int*)d_in[3];
    const float* Wl     = (const float*)d_in[4];
    const float* Wr     = (const float*)d_in[5];
    const float* att    = (const float*)d_in[6];
    const float* gat_b  = (const float*)d_in[7];
    const float* gcn_w  = (const float*)d_in[8];
    const float* gcn_b  = (const float*)d_in[9];
    const float* emb    = (const float*)d_in[10];
    const float* Wih_f  = (const float*)d_in[11];
    const float* Whh_f  = (const float*)d_in[12];
    const float* bih_f  = (const float*)d_in[13];
    const float* bhh_f  = (const float*)d_in[14];
    const float* Wih_b  = (const float*)d_in[15];
    const float* Whh_b  = (const float*)d_in[16];
    const float* bih_b  = (const float*)d_in[17];
    const float* bhh_b  = (const float*)d_in[18];
    const float* conv_w = (const float*)d_in[19];
    const float* conv_b = (const float*)d_in[20];
    const float* fcp_w  = (const float*)d_in[21];
    const float* fcp_b  = (const float*)d_in[22];
    const float* fc1_w  = (const float*)d_in[23];
    const float* fc1_b  = (const float*)d_in[24];
    const float* fc2_w  = (const float*)d_in[25];
    const float* fc2_b  = (const float*)d_in[26];
    const float* out_w  = (const float*)d_in[27];
    const float* out_b  = (const float*)d_in[28];
    float* out = (float*)d_out;
    (void)n_in; (void)in_sizes; (void)out_size;

    // ---------- workspace layout (phase-union to minimize footprint) ----------
    char* ws = (char*)d_ws;
    size_t o = 0;
    auto alloc = [&](size_t bytes) {
        char* p = ws + o;
        o = (o + bytes + 255) & ~(size_t)255;
        return p;
    };
    constexpr size_t BIG = (size_t)NN * DD * 4; // 93.6 MB
    // Union region: protein phase {hcat, proj26, convout} then graph phase {A_buf, B_buf}
    char* region = (char*)alloc(2 * BIG + 256);
    float* A_buf = (float*)region;                      // xl -> hw -> g... (f32)
    float* B_buf = (float*)(region + BIG);              // xr -> h(bf16) -> g
    float* hcat    = (float*)region;                                      // 32.8 MB
    float* proj26  = (float*)(region + (size_t)BB * SEQ * 128 * 4 + 256); // 53 KB
    float* convout = (float*)((char*)proj26 + 2 * 26 * 256 * 4 + 256);    // 1 MB
    __hip_bfloat16* h_bf = (__hip_bfloat16*)B_buf;      // aliases dead xr (46.8 MB)
    // Persistent buffers
    __hip_bfloat16* x_bf  = (__hip_bfloat16*)alloc((size_t)NN * CC * 2);
    __hip_bfloat16* wl_t  = (__hip_bfloat16*)alloc((size_t)DD * CC * 2);
    __hip_bfloat16* wr_t  = (__hip_bfloat16*)alloc((size_t)DD * CC * 2);
    __hip_bfloat16* gcw_t = (__hip_bfloat16*)alloc((size_t)DD * DD * 2);
    float* logit    = (float*)alloc((size_t)ET * HH * 4); // logits -> alpha in place
    int*   csr_src  = (int*)alloc((size_t)ET * 4);
    int*   csr_dst  = (int*)alloc((size_t)ET * 4);
    int*   deg      = (int*)alloc((size_t)NN * 4);
    int*   cursor   = (int*)alloc((size_t)NN * 4);
    int*   offs     = (int*)alloc((size_t)(NN + 1) * 4);
    float* dinv     = (float*)alloc((size_t)NN * 4);
    int*   gstart   = (int*)alloc(64 * 4);
    int*   gend     = (int*)alloc(64 * 4);
    float* comb     = (float*)alloc((size_t)BB * COMBD * 4);
    float* h1       = (float*)alloc((size_t)BB * 1024 * 4);
    float* h2       = (float*)alloc((size_t)BB * 512 * 4);
    if (o > ws_size) return;  // diagnostic: insufficient workspace -> no launches, no fault

    // zero scratch that is accumulated into (ws is NOT re-poisoned between replays)
    hipMemsetAsync(deg, 0, (size_t)NN * 4, stream);
    hipMemsetAsync(cursor, 0, (size_t)NN * 4, stream);
    hipMemsetAsync(gstart, 0, 64 * 4, stream);
    hipMemsetAsync(gend, 0, 64 * 4, stream);

    // ---------- protein branch (first: its buffers alias the graph region) ----------
    {
        dim3 grid(2, 26);
        proj26_kernel<<<grid, 256, 0, stream>>>(emb, Wih_f, bih_f, bhh_f, Wih_b, bih_b, bhh_b, proj26);
    }
    {
        dim3 grid(SEQ, 2);
        lstm_kernel<<<grid, 256, 0, stream>>>(target, proj26, Whh_f, Whh_b, hcat);
    }
    {
        dim3 grid(BB, 8);
        conv_kernel<<<grid, 128, 0, stream>>>(hcat, conv_w, conv_b, convout);
    }
    gemm_rowpar<0><<<(BB * 128 + 255) / 256, 256, 0, stream>>>(convout, fcp_w, fcp_b,
                                                               comb + 2 * DD, BB, 128, 3872, COMBD);

    // ---------- conversions for MFMA ----------
    f32_to_bf16<<<(NN * CC + 255) / 256, 256, 0, stream>>>(x, x_bf, NN * CC);
    transpose_to_bf16<<<(CC * DD + 255) / 256, 256, 0, stream>>>(Wl, wl_t, CC, DD);
    transpose_to_bf16<<<(CC * DD + 255) / 256, 256, 0, stream>>>(Wr, wr_t, CC, DD);
    transpose_to_bf16<<<(DD * DD + 255) / 256, 256, 0, stream>>>(gcn_w, gcw_t, DD, DD);

    // ---------- graph branch ----------
    dim3 ggrid((DD + 127) / 128, (NN + 127) / 128);
    // xl = x @ Wl (A_buf), xr = x @ Wr (B_buf)
    gemm_bf16_mfma<<<ggrid, 256, 0, stream>>>(x_bf, wl_t, A_buf, NN, DD, CC);
    gemm_bf16_mfma<<<ggrid, 256, 0, stream>>>(x_bf, wr_t, B_buf, NN, DD, CC);
    // CSR
    deg_count<<<(ET + 255) / 256, 256, 0, stream>>>(ei, deg);
    scan_kernel<<<1, 1024, 0, stream>>>(deg, offs);
    csr_fill<<<(ET + 255) / 256, 256, 0, stream>>>(ei, offs, cursor, csr_src, csr_dst);
    dinv_kernel<<<(NN + 255) / 256, 256, 0, stream>>>(deg, dinv);
    // GATv2: logits read A(xl)+B(xr); aggregate reads A+alpha, writes h_bf (aliases dead xr)
    gat_logits<<<(ET * HH + 255) / 256, 256, 0, stream>>>(A_buf, B_buf, att, csr_src, csr_dst, logit);
    gat_softmax<<<(NN * HH + 255) / 256, 256, 0, stream>>>(offs, logit);
    gat_aggregate<<<NN, 256, 0, stream>>>(offs, csr_src, logit, A_buf, gat_b, h_bf);
    // GCN: hw = h_bf @ gcn_w^T -> A_buf (xl dead); aggregate reads A, writes B (g, f32)
    gemm_bf16_mfma<<<ggrid, 256, 0, stream>>>(h_bf, gcw_t, A_buf, NN, DD, DD);
    gcn_aggregate<<<NN, 256, 0, stream>>>(offs, csr_src, dinv, A_buf, gcn_b, B_buf);
    // pooling -> comb[:, 0:1560]
    graph_ranges<<<(NN + 255) / 256, 256, 0, stream>>>(batch, gstart, gend);
    pool_kernel<<<BB, 256, 0, stream>>>(B_buf, gstart, gend, comb);

    // ---------- combined head ----------
    gemm_rowpar<1><<<(BB * 1024 + 255) / 256, 256, 0, stream>>>(comb, fc1_w, fc1_b, h1,
                                                                BB, 1024, COMBD, 1024);
    gemm_rowpar<1><<<(BB * 512 + 255) / 256, 256, 0, stream>>>(h1, fc2_w, fc2_b, h2,
                                                               BB, 512, 1024, 512);
    gemm_rowpar<0><<<1, 256, 0, stream>>>(h2, out_w, out_b, out, BB, 1, 512, 1);
}

// Round 4
// 2069.975 us; speedup vs baseline: 1.8474x; 1.1938x over previous
//
#include <hip/hip_runtime.h>
#include <hip/hip_bf16.h>
#include <math.h>

// Problem constants (fixed by setup_inputs)
static constexpr int NN   = 30000;   // nodes
static constexpr int EE   = 240000;  // edges (before self loops)
static constexpr int ET   = EE + NN; // edges incl self loops
static constexpr int BB   = 64;      // graphs
static constexpr int HH   = 10;      // heads
static constexpr int CC   = 78;      // per-head dim
static constexpr int DD   = HH * CC; // 780
static constexpr int SEQ  = 1000;
static constexpr int EMB  = 128;
static constexpr int LH   = 64;
static constexpr int COMBD = 2 * DD + 128; // 1688
static constexpr int PCHUNK = 64;    // nodes per pool_partial block

typedef __attribute__((ext_vector_type(8))) short short8;
typedef __attribute__((ext_vector_type(4))) float f32x4;

// ---------------- bf16 MFMA GEMM: C[M,N] = A[M,K] @ Bt[N,K]^T ----------------
__global__ __launch_bounds__(256) void gemm_bf16_mfma(const __hip_bfloat16* __restrict__ A,
                                                      const __hip_bfloat16* __restrict__ Bt,
                                                      float* __restrict__ C,
                                                      int M, int N, int K) {
    constexpr int LDS_S = 40;
    __shared__ unsigned short As[128 * LDS_S];
    __shared__ unsigned short Bs[128 * LDS_S];
    const int tid  = threadIdx.x;
    const int lane = tid & 63, wid = tid >> 6;
    const int wr = wid >> 1, wc = wid & 1;
    const int l15 = lane & 15, l4 = lane >> 4;
    const int bm = blockIdx.y * 128, bn = blockIdx.x * 128;
    const int tr = tid >> 2, tc = (tid & 3) * 8;

    const unsigned short* Au = (const unsigned short*)A;
    const unsigned short* Bu = (const unsigned short*)Bt;

    f32x4 acc[4][4];
#pragma unroll
    for (int m = 0; m < 4; ++m)
#pragma unroll
        for (int n = 0; n < 4; ++n) acc[m][n] = (f32x4){0.f, 0.f, 0.f, 0.f};

    for (int k0 = 0; k0 < K; k0 += 32) {
#pragma unroll
        for (int half = 0; half < 2; ++half) {
            int row = tr + half * 64;
            { // A tile
                int grow = bm + row;
                short8 sv;
                if (grow < M && k0 + tc + 8 <= K) {
                    const unsigned int* p = (const unsigned int*)(Au + (size_t)grow * K + k0 + tc);
#pragma unroll
                    for (int j = 0; j < 4; ++j) {
                        unsigned int u = p[j];
                        sv[2 * j]     = (short)(u & 0xffffu);
                        sv[2 * j + 1] = (short)(u >> 16);
                    }
                } else {
#pragma unroll
                    for (int j = 0; j < 8; ++j) {
                        int gk = k0 + tc + j;
                        sv[j] = (grow < M && gk < K) ? (short)Au[(size_t)grow * K + gk] : (short)0;
                    }
                }
                *reinterpret_cast<short8*>(&As[row * LDS_S + tc]) = sv;
            }
            { // B^T tile
                int grow = bn + row;
                short8 sv;
                if (grow < N && k0 + tc + 8 <= K) {
                    const unsigned int* p = (const unsigned int*)(Bu + (size_t)grow * K + k0 + tc);
#pragma unroll
                    for (int j = 0; j < 4; ++j) {
                        unsigned int u = p[j];
                        sv[2 * j]     = (short)(u & 0xffffu);
                        sv[2 * j + 1] = (short)(u >> 16);
                    }
                } else {
#pragma unroll
                    for (int j = 0; j < 8; ++j) {
                        int gk = k0 + tc + j;
                        sv[j] = (grow < N && gk < K) ? (short)Bu[(size_t)grow * K + gk] : (short)0;
                    }
                }
                *reinterpret_cast<short8*>(&Bs[row * LDS_S + tc]) = sv;
            }
        }
        __syncthreads();
        short8 a[4], b[4];
#pragma unroll
        for (int m = 0; m < 4; ++m)
            a[m] = *reinterpret_cast<const short8*>(&As[(wr * 64 + m * 16 + l15) * LDS_S + l4 * 8]);
#pragma unroll
        for (int n = 0; n < 4; ++n)
            b[n] = *reinterpret_cast<const short8*>(&Bs[(wc * 64 + n * 16 + l15) * LDS_S + l4 * 8]);
#pragma unroll
        for (int m = 0; m < 4; ++m)
#pragma unroll
            for (int n = 0; n < 4; ++n)
                acc[m][n] = __builtin_amdgcn_mfma_f32_16x16x32_bf16(a[m], b[n], acc[m][n], 0, 0, 0);
        __syncthreads();
    }
#pragma unroll
    for (int m = 0; m < 4; ++m)
#pragma unroll
        for (int n = 0; n < 4; ++n)
#pragma unroll
            for (int r = 0; r < 4; ++r) {
                int row = bm + wr * 64 + m * 16 + l4 * 4 + r;
                int col = bn + wc * 64 + n * 16 + l15;
                if (row < M && col < N) C[(size_t)row * N + col] = acc[m][n][r];
            }
}

// ---------------- conversions ----------------
__global__ void f32_to_bf16(const float* __restrict__ in, __hip_bfloat16* __restrict__ out, int n) {
    int i = blockIdx.x * blockDim.x + threadIdx.x;
    if (i < n) out[i] = __float2bfloat16(in[i]);
}

// in[K][N] f32 -> out[N][K] bf16
__global__ void transpose_to_bf16(const float* __restrict__ in, __hip_bfloat16* __restrict__ out,
                                  int Kdim, int Ndim) {
    int idx = blockIdx.x * blockDim.x + threadIdx.x;
    if (idx >= Kdim * Ndim) return;
    int n = idx / Kdim, k = idx % Kdim;
    out[idx] = __float2bfloat16(in[(size_t)k * Ndim + n]);
}

// ------------- small-M GEMM, thread per output: C = act(A@B + bias) -------------
template <int ACT>
__global__ void gemm_rowpar(const float* __restrict__ A, const float* __restrict__ B,
                            const float* __restrict__ bias, float* __restrict__ C,
                            int M, int N, int K, int ldc) {
    int idx = blockIdx.x * blockDim.x + threadIdx.x;
    if (idx >= M * N) return;
    int col = idx % N, row = idx / N;
    const float* a = A + (size_t)row * K;
    float acc = bias ? bias[col] : 0.f;
    int k = 0;
    for (; k + 3 < K; k += 4) {
        acc += a[k] * B[(size_t)k * N + col];
        acc += a[k + 1] * B[(size_t)(k + 1) * N + col];
        acc += a[k + 2] * B[(size_t)(k + 2) * N + col];
        acc += a[k + 3] * B[(size_t)(k + 3) * N + col];
    }
    for (; k < K; ++k) acc += a[k] * B[(size_t)k * N + col];
    if (ACT == 1) acc = fmaxf(acc, 0.f);
    C[(size_t)row * ldc + col] = acc;
}

// ---------------- CSR construction ----------------
__global__ void deg_count(const int* __restrict__ ei, int* __restrict__ deg) {
    int e = blockIdx.x * blockDim.x + threadIdx.x;
    if (e >= ET) return;
    int d = (e < EE) ? ei[EE + e] : (e - EE);
    atomicAdd(&deg[d], 1);
}

__global__ __launch_bounds__(1024) void scan_kernel(const int* __restrict__ deg,
                                                    int* __restrict__ offs) {
    __shared__ int lds[1024];
    int tid = threadIdx.x;
    const int chunk = (NN + 1023) / 1024;
    int base = tid * chunk;
    int s = 0;
    for (int i = 0; i < chunk; ++i) {
        int idx = base + i;
        if (idx < NN) s += deg[idx];
    }
    lds[tid] = s;
    __syncthreads();
    for (int d = 1; d < 1024; d <<= 1) {
        int v = (tid >= d) ? lds[tid - d] : 0;
        __syncthreads();
        lds[tid] += v;
        __syncthreads();
    }
    int run = (tid == 0) ? 0 : lds[tid - 1];
    for (int i = 0; i < chunk; ++i) {
        int idx = base + i;
        if (idx < NN) { offs[idx] = run; run += deg[idx]; }
    }
    if (tid == 1023) offs[NN] = lds[1023];
}

__global__ void csr_fill(const int* __restrict__ ei, const int* __restrict__ offs,
                         int* __restrict__ cursor, int* __restrict__ csr_src,
                         int* __restrict__ csr_dst) {
    int e = blockIdx.x * blockDim.x + threadIdx.x;
    if (e >= ET) return;
    int s = (e < EE) ? ei[e] : (e - EE);
    int d = (e < EE) ? ei[EE + e] : (e - EE);
    int pos = atomicAdd(&cursor[d], 1);
    int slot = offs[d] + pos;
    csr_src[slot] = s;
    csr_dst[slot] = d;
}

__global__ void dinv_kernel(const int* __restrict__ deg, float* __restrict__ dinv) {
    int n = blockIdx.x * blockDim.x + threadIdx.x;
    if (n >= NN) return;
    float dg = (float)deg[n];
    dinv[n] = (dg > 0.f) ? 1.f / sqrtf(dg) : 0.f;
}

// ---------------- GATv2 ----------------
__global__ void gat_logits(const float* __restrict__ xl, const float* __restrict__ xr,
                           const float* __restrict__ att, const int* __restrict__ csr_src,
                           const int* __restrict__ csr_dst, float* __restrict__ logit) {
    int idx = blockIdx.x * blockDim.x + threadIdx.x;
    if (idx >= ET * HH) return;
    int i = idx / HH, h = idx % HH;
    int s = csr_src[i], d = csr_dst[i];
    const float* pl = xl + (size_t)s * DD + h * CC;
    const float* pr = xr + (size_t)d * DD + h * CC;
    const float* pa = att + h * CC;
    float acc = 0.f;
    for (int c = 0; c < CC; ++c) {
        float v = pl[c] + pr[c];
        v = (v > 0.f) ? v : 0.2f * v;
        acc += pa[c] * v;
    }
    logit[idx] = acc;
}

__global__ void gat_softmax(const int* __restrict__ offs, float* __restrict__ logit) {
    int idx = blockIdx.x * blockDim.x + threadIdx.x;
    if (idx >= NN * HH) return;
    int n = idx / HH, h = idx % HH;
    int i0 = offs[n], i1 = offs[n + 1];
    float m = -1e30f;
    for (int i = i0; i < i1; ++i) m = fmaxf(m, logit[i * HH + h]);
    float den = 0.f;
    for (int i = i0; i < i1; ++i) {
        float e = expf(logit[i * HH + h] - m);
        logit[i * HH + h] = e;
        den += e;
    }
    float inv = 1.f / den;
    for (int i = i0; i < i1; ++i) logit[i * HH + h] *= inv;
}

// writes h as bf16 (consumed by the GCN MFMA GEMM)
__global__ __launch_bounds__(256) void gat_aggregate(const int* __restrict__ offs,
                                                     const int* __restrict__ csr_src,
                                                     const float* __restrict__ alpha,
                                                     const float* __restrict__ xl,
                                                     const float* __restrict__ gat_b,
                                                     __hip_bfloat16* __restrict__ hout) {
    int n = blockIdx.x;
    int i0 = offs[n], i1 = offs[n + 1];
    for (int d = threadIdx.x; d < DD; d += 256) {
        int h = d / CC;
        float acc = 0.f;
        for (int i = i0; i < i1; ++i)
            acc += alpha[i * HH + h] * xl[(size_t)csr_src[i] * DD + d];
        acc += gat_b[d];
        float v = (acc > 0.f) ? acc : expf(acc) - 1.f;
        hout[(size_t)n * DD + d] = __float2bfloat16(v);
    }
}

// ---------------- GCN aggregation ----------------
__global__ __launch_bounds__(256) void gcn_aggregate(const int* __restrict__ offs,
                                                     const int* __restrict__ csr_src,
                                                     const float* __restrict__ dinv,
                                                     const float* __restrict__ hw,
                                                     const float* __restrict__ gcn_b,
                                                     float* __restrict__ g) {
    int n = blockIdx.x;
    float din = dinv[n];
    int i0 = offs[n], i1 = offs[n + 1];
    for (int d = threadIdx.x; d < DD; d += 256) {
        float acc = 0.f;
        for (int i = i0; i < i1; ++i) {
            int s = csr_src[i];
            acc += dinv[s] * din * hw[(size_t)s * DD + d];
        }
        acc += gcn_b[d];
        g[(size_t)n * DD + d] = fmaxf(acc, 0.f);
    }
}

// ---------------- pooling ----------------
__global__ void graph_ranges(const int* __restrict__ batch, int* __restrict__ gstart,
                             int* __restrict__ gend) {
    int n = blockIdx.x * blockDim.x + threadIdx.x;
    if (n >= NN) return;
    int b = batch[n];
    if (n == 0 || batch[n - 1] != b) gstart[b] = n;
    if (n == NN - 1 || batch[n + 1] != b) gend[b] = n + 1;
}

// stage 1: chunk-of-nodes per block, coalesced row reads, atomic merge at
// sorted-batch boundaries. g >= 0 (ReLU), so atomicMax on uint bits is exact
// and zero-init matches the identity.
__global__ __launch_bounds__(256) void pool_partial(const float* __restrict__ g,
                                                    const int* __restrict__ batch,
                                                    float* __restrict__ pmax,
                                                    float* __restrict__ psum) {
    int chunk0 = blockIdx.x * PCHUNK;
    int tid = threadIdx.x;
    __shared__ int bsh[PCHUNK];
    for (int i = tid; i < PCHUNK; i += 256) {
        int n = chunk0 + i;
        bsh[i] = (n < NN) ? batch[n] : -1;
    }
    __syncthreads();
    float mx[4] = {0.f, 0.f, 0.f, 0.f};
    float sm[4] = {0.f, 0.f, 0.f, 0.f};
    int curb = bsh[0];
    auto flush = [&](int b) {
#pragma unroll
        for (int j = 0; j < 4; ++j) {
            int d = tid + j * 256;
            if (d < DD && b >= 0) {
                atomicMax((unsigned int*)&pmax[(size_t)b * DD + d], __float_as_uint(mx[j]));
                atomicAdd(&psum[(size_t)b * DD + d], sm[j]);
            }
            mx[j] = 0.f; sm[j] = 0.f;
        }
    };
    for (int i = 0; i < PCHUNK; ++i) {
        int n = chunk0 + i;
        if (n >= NN) break;
        int b = bsh[i];
        if (b != curb) { flush(curb); curb = b; }
        const float* row = g + (size_t)n * DD;
#pragma unroll
        for (int j = 0; j < 4; ++j) {
            int d = tid + j * 256;
            if (d < DD) {
                float v = row[d];
                mx[j] = fmaxf(mx[j], v);
                sm[j] += v;
            }
        }
    }
    flush(curb);
}

// stage 2: write comb layout
__global__ void pool_finalize(const float* __restrict__ pmax, const float* __restrict__ psum,
                              const int* __restrict__ gstart, const int* __restrict__ gend,
                              float* __restrict__ comb) {
    int idx = blockIdx.x * blockDim.x + threadIdx.x;
    if (idx >= BB * DD) return;
    int b = idx / DD, d = idx % DD;
    float cnt = fmaxf((float)(gend[b] - gstart[b]), 1.f);
    comb[(size_t)b * COMBD + d] = pmax[idx];
    comb[(size_t)b * COMBD + DD + d] = psum[idx] / cnt;
}

// ---------------- protein branch ----------------
__global__ void proj26_kernel(const float* __restrict__ emb,
                              const float* __restrict__ Wih_f, const float* __restrict__ bih_f,
                              const float* __restrict__ bhh_f,
                              const float* __restrict__ Wih_b, const float* __restrict__ bih_b,
                              const float* __restrict__ bhh_b, float* __restrict__ proj) {
    int dir = blockIdx.x, row = blockIdx.y, j = threadIdx.x;
    const float* W = dir ? Wih_b : Wih_f;
    const float* b1 = dir ? bih_b : bih_f;
    const float* b2 = dir ? bhh_b : bhh_f;
    float acc = b1[j] + b2[j];
    const float* e = emb + row * EMB;
    const float* w = W + j * EMB;
    for (int k = 0; k < EMB; ++k) acc += e[k] * w[k];
    proj[(dir * 26 + row) * 256 + j] = acc;
}

__global__ __launch_bounds__(256) void lstm_kernel(const int* __restrict__ target,
                                                   const float* __restrict__ proj26,
                                                   const float* __restrict__ Whh_f,
                                                   const float* __restrict__ Whh_b,
                                                   float* __restrict__ hcat) {
    int n = blockIdx.x;      // 0..999 (sequence position == LSTM batch element)
    int dir = blockIdx.y;    // 0 fwd, 1 bwd
    int tid = threadIdx.x;   // 0..255 (gate unit)
    const float* Whh = dir ? Whh_b : Whh_f;
    const float* proj = proj26 + dir * 26 * 256;
    float w[LH];
#pragma unroll
    for (int u4 = 0; u4 < LH / 4; ++u4) {
        float4 v = *reinterpret_cast<const float4*>(Whh + tid * LH + u4 * 4);
        w[u4 * 4 + 0] = v.x; w[u4 * 4 + 1] = v.y;
        w[u4 * 4 + 2] = v.z; w[u4 * 4 + 3] = v.w;
    }
    __shared__ float h_lds[LH];
    __shared__ float c_lds[LH];
    __shared__ float z_lds[256];
    if (tid < LH) { h_lds[tid] = 0.f; c_lds[tid] = 0.f; }
    __syncthreads();
    for (int s = 0; s < BB; ++s) {
        int t = dir ? (BB - 1 - s) : s;
        int tgt = target[t * SEQ + n];
        float a0 = 0.f, a1 = 0.f, a2 = 0.f, a3 = 0.f;
#pragma unroll
        for (int u = 0; u < LH; u += 4) {
            a0 += w[u] * h_lds[u];
            a1 += w[u + 1] * h_lds[u + 1];
            a2 += w[u + 2] * h_lds[u + 2];
            a3 += w[u + 3] * h_lds[u + 3];
        }
        z_lds[tid] = proj[tgt * 256 + tid] + a0 + a1 + a2 + a3;
        __syncthreads();
        if (tid < LH) {
            float ig = 1.f / (1.f + expf(-z_lds[tid]));
            float fg = 1.f / (1.f + expf(-z_lds[LH + tid]));
            float gg = tanhf(z_lds[2 * LH + tid]);
            float og = 1.f / (1.f + expf(-z_lds[3 * LH + tid]));
            float c = fg * c_lds[tid] + ig * gg;
            float h = og * tanhf(c);
            c_lds[tid] = c;
            h_lds[tid] = h;
            hcat[((size_t)t * SEQ + n) * 128 + dir * LH + tid] = h;
        }
        __syncthreads();
    }
}

__global__ void conv_kernel(const float* __restrict__ hcat, const float* __restrict__ conv_w,
                            const float* __restrict__ conv_b, float* __restrict__ convout) {
    int b = blockIdx.x;   // 64
    int og = blockIdx.y;  // 8 groups of 4 out channels
    int p = threadIdx.x;  // 0..127
    if (p >= 121) return;
    float acc[4] = {0.f, 0.f, 0.f, 0.f};
    for (int i = 0; i < SEQ; ++i) {
        const float* hrow = hcat + ((size_t)b * SEQ + i) * 128;
        float x[8];
#pragma unroll
        for (int k = 0; k < 8; ++k) x[k] = hrow[p + k];
#pragma unroll
        for (int oo = 0; oo < 4; ++oo) {
            const float* wr = conv_w + ((size_t)(og * 4 + oo) * SEQ + i) * 8;
#pragma unroll
            for (int k = 0; k < 8; ++k) acc[oo] += x[k] * wr[k];
        }
    }
#pragma unroll
    for (int oo = 0; oo < 4; ++oo) {
        int o = og * 4 + oo;
        convout[(size_t)b * 3872 + o * 121 + p] = acc[oo] + conv_b[o];
    }
}

// ---------------- launcher ----------------
extern "C" void kernel_launch(void* const* d_in, const int* in_sizes, int n_in,
                              void* d_out, int out_size, void* d_ws, size_t ws_size,
                              hipStream_t stream) {
    const float* x      = (const float*)d_in[0];
    const int*   ei     = (const int*)d_in[1];
    const int*   batch  = (const int*)d_in[2];
    const int*   target = (const int*)d_in[3];
    const float* Wl     = (const float*)d_in[4];
    const float* Wr     = (const float*)d_in[5];
    const float* att    = (const float*)d_in[6];
    const float* gat_b  = (const float*)d_in[7];
    const float* gcn_w  = (const float*)d_in[8];
    const float* gcn_b  = (const float*)d_in[9];
    const float* emb    = (const float*)d_in[10];
    const float* Wih_f  = (const float*)d_in[11];
    const float* Whh_f  = (const float*)d_in[12];
    const float* bih_f  = (const float*)d_in[13];
    const float* bhh_f  = (const float*)d_in[14];
    const float* Wih_b  = (const float*)d_in[15];
    const float* Whh_b  = (const float*)d_in[16];
    const float* bih_b  = (const float*)d_in[17];
    const float* bhh_b  = (const float*)d_in[18];
    const float* conv_w = (const float*)d_in[19];
    const float* conv_b = (const float*)d_in[20];
    const float* fcp_w  = (const float*)d_in[21];
    const float* fcp_b  = (const float*)d_in[22];
    const float* fc1_w  = (const float*)d_in[23];
    const float* fc1_b  = (const float*)d_in[24];
    const float* fc2_w  = (const float*)d_in[25];
    const float* fc2_b  = (const float*)d_in[26];
    const float* out_w  = (const float*)d_in[27];
    const float* out_b  = (const float*)d_in[28];
    float* out = (float*)d_out;
    (void)n_in; (void)in_sizes; (void)out_size;

    // ---------- workspace layout (phase-union to minimize footprint) ----------
    char* ws = (char*)d_ws;
    size_t o = 0;
    auto alloc = [&](size_t bytes) {
        char* p = ws + o;
        o = (o + bytes + 255) & ~(size_t)255;
        return p;
    };
    constexpr size_t BIG = (size_t)NN * DD * 4; // 93.6 MB
    // Union region: protein phase {hcat, proj26, convout} then graph phase {A_buf, B_buf}
    char* region = (char*)alloc(2 * BIG + 256);
    float* A_buf = (float*)region;                      // xl -> hw (f32)
    float* B_buf = (float*)(region + BIG);              // xr -> h(bf16) -> g
    float* hcat    = (float*)region;                                      // 32.8 MB
    float* proj26  = (float*)(region + (size_t)BB * SEQ * 128 * 4 + 256); // 53 KB
    float* convout = (float*)((char*)proj26 + 2 * 26 * 256 * 4 + 256);    // 1 MB
    __hip_bfloat16* h_bf = (__hip_bfloat16*)B_buf;      // aliases dead xr (46.8 MB)
    // Persistent buffers
    __hip_bfloat16* x_bf  = (__hip_bfloat16*)alloc((size_t)NN * CC * 2);
    __hip_bfloat16* wl_t  = (__hip_bfloat16*)alloc((size_t)DD * CC * 2);
    __hip_bfloat16* wr_t  = (__hip_bfloat16*)alloc((size_t)DD * CC * 2);
    __hip_bfloat16* gcw_t = (__hip_bfloat16*)alloc((size_t)DD * DD * 2);
    float* logit    = (float*)alloc((size_t)ET * HH * 4); // logits -> alpha in place
    int*   csr_src  = (int*)alloc((size_t)ET * 4);
    int*   csr_dst  = (int*)alloc((size_t)ET * 4);
    int*   deg      = (int*)alloc((size_t)NN * 4);
    int*   cursor   = (int*)alloc((size_t)NN * 4);
    int*   offs     = (int*)alloc((size_t)(NN + 1) * 4);
    float* dinv     = (float*)alloc((size_t)NN * 4);
    int*   gstart   = (int*)alloc(64 * 4);
    int*   gend     = (int*)alloc(64 * 4);
    float* pmax     = (float*)alloc((size_t)BB * DD * 4);
    float* psum     = (float*)alloc((size_t)BB * DD * 4);
    float* comb     = (float*)alloc((size_t)BB * COMBD * 4);
    float* h1       = (float*)alloc((size_t)BB * 1024 * 4);
    float* h2       = (float*)alloc((size_t)BB * 512 * 4);
    if (o > ws_size) return;  // diagnostic: insufficient workspace -> no launches, no fault

    // zero scratch that is accumulated into (ws is NOT re-poisoned between replays)
    hipMemsetAsync(deg, 0, (size_t)NN * 4, stream);
    hipMemsetAsync(cursor, 0, (size_t)NN * 4, stream);
    hipMemsetAsync(gstart, 0, 64 * 4, stream);
    hipMemsetAsync(gend, 0, 64 * 4, stream);
    hipMemsetAsync(pmax, 0, (size_t)BB * DD * 4, stream);
    hipMemsetAsync(psum, 0, (size_t)BB * DD * 4, stream);

    // ---------- protein branch (first: its buffers alias the graph region) ----------
    {
        dim3 grid(2, 26);
        proj26_kernel<<<grid, 256, 0, stream>>>(emb, Wih_f, bih_f, bhh_f, Wih_b, bih_b, bhh_b, proj26);
    }
    {
        dim3 grid(SEQ, 2);
        lstm_kernel<<<grid, 256, 0, stream>>>(target, proj26, Whh_f, Whh_b, hcat);
    }
    {
        dim3 grid(BB, 8);
        conv_kernel<<<grid, 128, 0, stream>>>(hcat, conv_w, conv_b, convout);
    }
    gemm_rowpar<0><<<(BB * 128 + 255) / 256, 256, 0, stream>>>(convout, fcp_w, fcp_b,
                                                               comb + 2 * DD, BB, 128, 3872, COMBD);

    // ---------- conversions for MFMA ----------
    f32_to_bf16<<<(NN * CC + 255) / 256, 256, 0, stream>>>(x, x_bf, NN * CC);
    transpose_to_bf16<<<(CC * DD + 255) / 256, 256, 0, stream>>>(Wl, wl_t, CC, DD);
    transpose_to_bf16<<<(CC * DD + 255) / 256, 256, 0, stream>>>(Wr, wr_t, CC, DD);
    transpose_to_bf16<<<(DD * DD + 255) / 256, 256, 0, stream>>>(gcn_w, gcw_t, DD, DD);

    // ---------- graph branch ----------
    dim3 ggrid((DD + 127) / 128, (NN + 127) / 128);
    // xl = x @ Wl (A_buf), xr = x @ Wr (B_buf)
    gemm_bf16_mfma<<<ggrid, 256, 0, stream>>>(x_bf, wl_t, A_buf, NN, DD, CC);
    gemm_bf16_mfma<<<ggrid, 256, 0, stream>>>(x_bf, wr_t, B_buf, NN, DD, CC);
    // CSR
    deg_count<<<(ET + 255) / 256, 256, 0, stream>>>(ei, deg);
    scan_kernel<<<1, 1024, 0, stream>>>(deg, offs);
    csr_fill<<<(ET + 255) / 256, 256, 0, stream>>>(ei, offs, cursor, csr_src, csr_dst);
    dinv_kernel<<<(NN + 255) / 256, 256, 0, stream>>>(deg, dinv);
    // GATv2: logits read A(xl)+B(xr); aggregate reads A+alpha, writes h_bf (aliases dead xr)
    gat_logits<<<(ET * HH + 255) / 256, 256, 0, stream>>>(A_buf, B_buf, att, csr_src, csr_dst, logit);
    gat_softmax<<<(NN * HH + 255) / 256, 256, 0, stream>>>(offs, logit);
    gat_aggregate<<<NN, 256, 0, stream>>>(offs, csr_src, logit, A_buf, gat_b, h_bf);
    // GCN: hw = h_bf @ gcn_w^T -> A_buf (xl dead); aggregate reads A, writes B (g, f32)
    gemm_bf16_mfma<<<ggrid, 256, 0, stream>>>(h_bf, gcw_t, A_buf, NN, DD, DD);
    gcn_aggregate<<<NN, 256, 0, stream>>>(offs, csr_src, dinv, A_buf, gcn_b, B_buf);
    // pooling -> comb[:, 0:1560]
    graph_ranges<<<(NN + 255) / 256, 256, 0, stream>>>(batch, gstart, gend);
    pool_partial<<<(NN + PCHUNK - 1) / PCHUNK, 256, 0, stream>>>(B_buf, batch, pmax, psum);
    pool_finalize<<<(BB * DD + 255) / 256, 256, 0, stream>>>(pmax, psum, gstart, gend, comb);

    // ---------- combined head ----------
    gemm_rowpar<1><<<(BB * 1024 + 255) / 256, 256, 0, stream>>>(comb, fc1_w, fc1_b, h1,
                                                                BB, 1024, COMBD, 1024);
    gemm_rowpar<1><<<(BB * 512 + 255) / 256, 256, 0, stream>>>(h1, fc2_w, fc2_b, h2,
                                                               BB, 512, 1024, 512);
    gemm_rowpar<0><<<1, 256, 0, stream>>>(h2, out_w, out_b, out, BB, 1, 512, 1);
}

// Round 5
// 1256.966 us; speedup vs baseline: 3.0424x; 1.6468x over previous
//
#include <hip/hip_runtime.h>
#include <hip/hip_bf16.h>
#include <math.h>

// Problem constants (fixed by setup_inputs)
static constexpr int NN   = 30000;   // nodes
static constexpr int EE   = 240000;  // edges (before self loops)
static constexpr int ET   = EE + NN; // edges incl self loops
static constexpr int BB   = 64;      // graphs
static constexpr int HH   = 10;      // heads
static constexpr int CC   = 78;      // per-head dim
static constexpr int DD   = HH * CC; // 780
static constexpr int SEQ  = 1000;
static constexpr int EMB  = 128;
static constexpr int LH   = 64;
static constexpr int COMBD = 2 * DD + 128; // 1688
static constexpr int PCHUNK = 64;    // nodes per pool_partial block

typedef __attribute__((ext_vector_type(8))) short short8;
typedef __attribute__((ext_vector_type(4))) float f32x4;

__device__ __forceinline__ float bf2f(unsigned short u) {
    return __uint_as_float(((unsigned int)u) << 16);
}

// ---------------- bf16 MFMA GEMM: C[M,N] = A[M,K] @ Bt[N,K]^T ----------------
// OBF=1 -> C stored as bf16, else f32. f32 accumulation via MFMA.
template <int OBF>
__global__ __launch_bounds__(256) void gemm_bf16_mfma(const __hip_bfloat16* __restrict__ A,
                                                      const __hip_bfloat16* __restrict__ Bt,
                                                      void* __restrict__ Cv,
                                                      int M, int N, int K) {
    constexpr int LDS_S = 40;
    __shared__ unsigned short As[128 * LDS_S];
    __shared__ unsigned short Bs[128 * LDS_S];
    const int tid  = threadIdx.x;
    const int lane = tid & 63, wid = tid >> 6;
    const int wr = wid >> 1, wc = wid & 1;
    const int l15 = lane & 15, l4 = lane >> 4;
    const int bm = blockIdx.y * 128, bn = blockIdx.x * 128;
    const int tr = tid >> 2, tc = (tid & 3) * 8;

    const unsigned short* Au = (const unsigned short*)A;
    const unsigned short* Bu = (const unsigned short*)Bt;

    f32x4 acc[4][4];
#pragma unroll
    for (int m = 0; m < 4; ++m)
#pragma unroll
        for (int n = 0; n < 4; ++n) acc[m][n] = (f32x4){0.f, 0.f, 0.f, 0.f};

    for (int k0 = 0; k0 < K; k0 += 32) {
#pragma unroll
        for (int half = 0; half < 2; ++half) {
            int row = tr + half * 64;
            { // A tile
                int grow = bm + row;
                short8 sv;
                if (grow < M && k0 + tc + 8 <= K) {
                    const unsigned int* p = (const unsigned int*)(Au + (size_t)grow * K + k0 + tc);
#pragma unroll
                    for (int j = 0; j < 4; ++j) {
                        unsigned int u = p[j];
                        sv[2 * j]     = (short)(u & 0xffffu);
                        sv[2 * j + 1] = (short)(u >> 16);
                    }
                } else {
#pragma unroll
                    for (int j = 0; j < 8; ++j) {
                        int gk = k0 + tc + j;
                        sv[j] = (grow < M && gk < K) ? (short)Au[(size_t)grow * K + gk] : (short)0;
                    }
                }
                *reinterpret_cast<short8*>(&As[row * LDS_S + tc]) = sv;
            }
            { // B^T tile
                int grow = bn + row;
                short8 sv;
                if (grow < N && k0 + tc + 8 <= K) {
                    const unsigned int* p = (const unsigned int*)(Bu + (size_t)grow * K + k0 + tc);
#pragma unroll
                    for (int j = 0; j < 4; ++j) {
                        unsigned int u = p[j];
                        sv[2 * j]     = (short)(u & 0xffffu);
                        sv[2 * j + 1] = (short)(u >> 16);
                    }
                } else {
#pragma unroll
                    for (int j = 0; j < 8; ++j) {
                        int gk = k0 + tc + j;
                        sv[j] = (grow < N && gk < K) ? (short)Bu[(size_t)grow * K + gk] : (short)0;
                    }
                }
                *reinterpret_cast<short8*>(&Bs[row * LDS_S + tc]) = sv;
            }
        }
        __syncthreads();
        short8 a[4], b[4];
#pragma unroll
        for (int m = 0; m < 4; ++m)
            a[m] = *reinterpret_cast<const short8*>(&As[(wr * 64 + m * 16 + l15) * LDS_S + l4 * 8]);
#pragma unroll
        for (int n = 0; n < 4; ++n)
            b[n] = *reinterpret_cast<const short8*>(&Bs[(wc * 64 + n * 16 + l15) * LDS_S + l4 * 8]);
#pragma unroll
        for (int m = 0; m < 4; ++m)
#pragma unroll
            for (int n = 0; n < 4; ++n)
                acc[m][n] = __builtin_amdgcn_mfma_f32_16x16x32_bf16(a[m], b[n], acc[m][n], 0, 0, 0);
        __syncthreads();
    }
#pragma unroll
    for (int m = 0; m < 4; ++m)
#pragma unroll
        for (int n = 0; n < 4; ++n)
#pragma unroll
            for (int r = 0; r < 4; ++r) {
                int row = bm + wr * 64 + m * 16 + l4 * 4 + r;
                int col = bn + wc * 64 + n * 16 + l15;
                if (row < M && col < N) {
                    if (OBF)
                        ((__hip_bfloat16*)Cv)[(size_t)row * N + col] = __float2bfloat16(acc[m][n][r]);
                    else
                        ((float*)Cv)[(size_t)row * N + col] = acc[m][n][r];
                }
            }
}

// ---------------- conversions ----------------
__global__ void f32_to_bf16(const float* __restrict__ in, __hip_bfloat16* __restrict__ out, int n) {
    int i = blockIdx.x * blockDim.x + threadIdx.x;
    if (i < n) out[i] = __float2bfloat16(in[i]);
}

// in[K][N] f32 -> out[N][K] bf16
__global__ void transpose_to_bf16(const float* __restrict__ in, __hip_bfloat16* __restrict__ out,
                                  int Kdim, int Ndim) {
    int idx = blockIdx.x * blockDim.x + threadIdx.x;
    if (idx >= Kdim * Ndim) return;
    int n = idx / Kdim, k = idx % Kdim;
    out[idx] = __float2bfloat16(in[(size_t)k * Ndim + n]);
}

// in[K][N] f32 -> out[N][K] f32
__global__ void transpose_f32(const float* __restrict__ in, float* __restrict__ out,
                              int Kdim, int Ndim) {
    int idx = blockIdx.x * blockDim.x + threadIdx.x;
    if (idx >= Kdim * Ndim) return;
    int n = idx / Kdim, k = idx % Kdim;
    out[idx] = in[(size_t)k * Ndim + n];
}

// ------------- skinny GEMM: wave-per-output split-K. Bt is [N][K]. -------------
template <int ACT>
__global__ __launch_bounds__(256) void gemm_skinny(const float* __restrict__ A,
                                                   const float* __restrict__ Bt,
                                                   const float* __restrict__ bias,
                                                   float* __restrict__ C,
                                                   int M, int N, int K, int ldc) {
    int oidx = blockIdx.x * 4 + (threadIdx.x >> 6);
    int lane = threadIdx.x & 63;
    if (oidx >= M * N) return;
    int row = oidx / N, col = oidx % N;
    const float4* a = (const float4*)(A + (size_t)row * K);
    const float4* b = (const float4*)(Bt + (size_t)col * K);
    int K4 = K >> 2;
    float s = 0.f;
    for (int i = lane; i < K4; i += 64) {
        float4 x = a[i], y = b[i];
        s += x.x * y.x + x.y * y.y + x.z * y.z + x.w * y.w;
    }
#pragma unroll
    for (int off = 32; off; off >>= 1) s += __shfl_xor(s, off);
    if (lane == 0) {
        s += bias[col];
        if (ACT == 1) s = fmaxf(s, 0.f);
        C[(size_t)row * ldc + col] = s;
    }
}

// ---------------- CSR construction ----------------
__global__ void deg_count(const int* __restrict__ ei, int* __restrict__ deg) {
    int e = blockIdx.x * blockDim.x + threadIdx.x;
    if (e >= ET) return;
    int d = (e < EE) ? ei[EE + e] : (e - EE);
    atomicAdd(&deg[d], 1);
}

__global__ __launch_bounds__(1024) void scan_kernel(const int* __restrict__ deg,
                                                    int* __restrict__ offs) {
    __shared__ int lds[1024];
    int tid = threadIdx.x;
    const int chunk = (NN + 1023) / 1024;
    int base = tid * chunk;
    int s = 0;
    for (int i = 0; i < chunk; ++i) {
        int idx = base + i;
        if (idx < NN) s += deg[idx];
    }
    lds[tid] = s;
    __syncthreads();
    for (int d = 1; d < 1024; d <<= 1) {
        int v = (tid >= d) ? lds[tid - d] : 0;
        __syncthreads();
        lds[tid] += v;
        __syncthreads();
    }
    int run = (tid == 0) ? 0 : lds[tid - 1];
    for (int i = 0; i < chunk; ++i) {
        int idx = base + i;
        if (idx < NN) { offs[idx] = run; run += deg[idx]; }
    }
    if (tid == 1023) offs[NN] = lds[1023];
}

__global__ void csr_fill(const int* __restrict__ ei, const int* __restrict__ offs,
                         int* __restrict__ cursor, int* __restrict__ csr_src,
                         int* __restrict__ csr_dst) {
    int e = blockIdx.x * blockDim.x + threadIdx.x;
    if (e >= ET) return;
    int s = (e < EE) ? ei[e] : (e - EE);
    int d = (e < EE) ? ei[EE + e] : (e - EE);
    int pos = atomicAdd(&cursor[d], 1);
    int slot = offs[d] + pos;
    csr_src[slot] = s;
    csr_dst[slot] = d;
}

__global__ void dinv_kernel(const int* __restrict__ deg, float* __restrict__ dinv) {
    int n = blockIdx.x * blockDim.x + threadIdx.x;
    if (n >= NN) return;
    float dg = (float)deg[n];
    dinv[n] = (dg > 0.f) ? 1.f / sqrtf(dg) : 0.f;
}

// ---------------- GATv2 (bf16 gathers, f32 accumulation) ----------------
__global__ void gat_logits(const unsigned short* __restrict__ xl,
                           const unsigned short* __restrict__ xr,
                           const float* __restrict__ att, const int* __restrict__ csr_src,
                           const int* __restrict__ csr_dst, float* __restrict__ logit) {
    int idx = blockIdx.x * blockDim.x + threadIdx.x;
    if (idx >= ET * HH) return;
    int i = idx / HH, h = idx % HH;
    int s = csr_src[i], d = csr_dst[i];
    const unsigned int* pl = (const unsigned int*)(xl + (size_t)s * DD + h * CC);
    const unsigned int* pr = (const unsigned int*)(xr + (size_t)d * DD + h * CC);
    const float* pa = att + h * CC;
    float acc = 0.f;
#pragma unroll
    for (int c = 0; c < CC / 2; ++c) {
        unsigned int a = pl[c], b = pr[c];
        float v0 = __uint_as_float((a & 0xffffu) << 16) + __uint_as_float((b & 0xffffu) << 16);
        float v1 = __uint_as_float(a & 0xffff0000u) + __uint_as_float(b & 0xffff0000u);
        v0 = (v0 > 0.f) ? v0 : 0.2f * v0;
        v1 = (v1 > 0.f) ? v1 : 0.2f * v1;
        acc += pa[2 * c] * v0 + pa[2 * c + 1] * v1;
    }
    logit[idx] = acc;
}

__global__ void gat_softmax(const int* __restrict__ offs, float* __restrict__ logit) {
    int idx = blockIdx.x * blockDim.x + threadIdx.x;
    if (idx >= NN * HH) return;
    int n = idx / HH, h = idx % HH;
    int i0 = offs[n], i1 = offs[n + 1];
    float m = -1e30f;
    for (int i = i0; i < i1; ++i) m = fmaxf(m, logit[i * HH + h]);
    float den = 0.f;
    for (int i = i0; i < i1; ++i) {
        float e = expf(logit[i * HH + h] - m);
        logit[i * HH + h] = e;
        den += e;
    }
    float inv = 1.f / den;
    for (int i = i0; i < i1; ++i) logit[i * HH + h] *= inv;
}

// reads bf16 xl, writes bf16 h
__global__ __launch_bounds__(256) void gat_aggregate(const int* __restrict__ offs,
                                                     const int* __restrict__ csr_src,
                                                     const float* __restrict__ alpha,
                                                     const unsigned short* __restrict__ xl,
                                                     const float* __restrict__ gat_b,
                                                     __hip_bfloat16* __restrict__ hout) {
    int n = blockIdx.x;
    int tid = threadIdx.x;
    int i0 = offs[n], i1 = offs[n + 1];
    int d0 = tid, d1 = tid + 256, d2 = tid + 512, d3 = tid + 768;
    int h0 = d0 / CC, h1 = d1 / CC, h2 = d2 / CC, h3 = (d3 < DD) ? d3 / CC : 0;
    float a0 = 0.f, a1 = 0.f, a2 = 0.f, a3 = 0.f;
    for (int i = i0; i < i1; ++i) {
        const unsigned short* row = xl + (size_t)csr_src[i] * DD;
        const float* al = alpha + (size_t)i * HH;
        a0 += al[h0] * bf2f(row[d0]);
        a1 += al[h1] * bf2f(row[d1]);
        a2 += al[h2] * bf2f(row[d2]);
        if (d3 < DD) a3 += al[h3] * bf2f(row[d3]);
    }
    float v;
    v = a0 + gat_b[d0]; v = (v > 0.f) ? v : expf(v) - 1.f;
    hout[(size_t)n * DD + d0] = __float2bfloat16(v);
    v = a1 + gat_b[d1]; v = (v > 0.f) ? v : expf(v) - 1.f;
    hout[(size_t)n * DD + d1] = __float2bfloat16(v);
    v = a2 + gat_b[d2]; v = (v > 0.f) ? v : expf(v) - 1.f;
    hout[(size_t)n * DD + d2] = __float2bfloat16(v);
    if (d3 < DD) {
        v = a3 + gat_b[d3]; v = (v > 0.f) ? v : expf(v) - 1.f;
        hout[(size_t)n * DD + d3] = __float2bfloat16(v);
    }
}

// ---------------- GCN aggregation (bf16 in, bf16 out) ----------------
__global__ __launch_bounds__(256) void gcn_aggregate(const int* __restrict__ offs,
                                                     const int* __restrict__ csr_src,
                                                     const float* __restrict__ dinv,
                                                     const unsigned short* __restrict__ hw,
                                                     const float* __restrict__ gcn_b,
                                                     __hip_bfloat16* __restrict__ g) {
    int n = blockIdx.x;
    int tid = threadIdx.x;
    float din = dinv[n];
    int i0 = offs[n], i1 = offs[n + 1];
    int d0 = tid, d1 = tid + 256, d2 = tid + 512, d3 = tid + 768;
    float a0 = 0.f, a1 = 0.f, a2 = 0.f, a3 = 0.f;
    for (int i = i0; i < i1; ++i) {
        int s = csr_src[i];
        float w = dinv[s] * din;
        const unsigned short* row = hw + (size_t)s * DD;
        a0 += w * bf2f(row[d0]);
        a1 += w * bf2f(row[d1]);
        a2 += w * bf2f(row[d2]);
        if (d3 < DD) a3 += w * bf2f(row[d3]);
    }
    g[(size_t)n * DD + d0] = __float2bfloat16(fmaxf(a0 + gcn_b[d0], 0.f));
    g[(size_t)n * DD + d1] = __float2bfloat16(fmaxf(a1 + gcn_b[d1], 0.f));
    g[(size_t)n * DD + d2] = __float2bfloat16(fmaxf(a2 + gcn_b[d2], 0.f));
    if (d3 < DD) g[(size_t)n * DD + d3] = __float2bfloat16(fmaxf(a3 + gcn_b[d3], 0.f));
}

// ---------------- pooling ----------------
__global__ void graph_ranges(const int* __restrict__ batch, int* __restrict__ gstart,
                             int* __restrict__ gend) {
    int n = blockIdx.x * blockDim.x + threadIdx.x;
    if (n >= NN) return;
    int b = batch[n];
    if (n == 0 || batch[n - 1] != b) gstart[b] = n;
    if (n == NN - 1 || batch[n + 1] != b) gend[b] = n + 1;
}

// stage 1: chunk-of-nodes per block, coalesced bf16 row reads, atomic merge at
// sorted-batch boundaries. g >= 0 (ReLU): atomicMax on uint bits exact, zero-init ok.
__global__ __launch_bounds__(256) void pool_partial(const unsigned short* __restrict__ g,
                                                    const int* __restrict__ batch,
                                                    float* __restrict__ pmax,
                                                    float* __restrict__ psum) {
    int chunk0 = blockIdx.x * PCHUNK;
    int tid = threadIdx.x;
    __shared__ int bsh[PCHUNK];
    for (int i = tid; i < PCHUNK; i += 256) {
        int n = chunk0 + i;
        bsh[i] = (n < NN) ? batch[n] : -1;
    }
    __syncthreads();
    float mx[4] = {0.f, 0.f, 0.f, 0.f};
    float sm[4] = {0.f, 0.f, 0.f, 0.f};
    int curb = bsh[0];
    auto flush = [&](int b) {
#pragma unroll
        for (int j = 0; j < 4; ++j) {
            int d = tid + j * 256;
            if (d < DD && b >= 0) {
                atomicMax((unsigned int*)&pmax[(size_t)b * DD + d], __float_as_uint(mx[j]));
                atomicAdd(&psum[(size_t)b * DD + d], sm[j]);
            }
            mx[j] = 0.f; sm[j] = 0.f;
        }
    };
    for (int i = 0; i < PCHUNK; ++i) {
        int n = chunk0 + i;
        if (n >= NN) break;
        int b = bsh[i];
        if (b != curb) { flush(curb); curb = b; }
        const unsigned short* row = g + (size_t)n * DD;
#pragma unroll
        for (int j = 0; j < 4; ++j) {
            int d = tid + j * 256;
            if (d < DD) {
                float v = bf2f(row[d]);
                mx[j] = fmaxf(mx[j], v);
                sm[j] += v;
            }
        }
    }
    flush(curb);
}

// stage 2: write comb layout
__global__ void pool_finalize(const float* __restrict__ pmax, const float* __restrict__ psum,
                              const int* __restrict__ gstart, const int* __restrict__ gend,
                              float* __restrict__ comb) {
    int idx = blockIdx.x * blockDim.x + threadIdx.x;
    if (idx >= BB * DD) return;
    int b = idx / DD, d = idx % DD;
    float cnt = fmaxf((float)(gend[b] - gstart[b]), 1.f);
    comb[(size_t)b * COMBD + d] = pmax[idx];
    comb[(size_t)b * COMBD + DD + d] = psum[idx] / cnt;
}

// ---------------- protein branch ----------------
__global__ void proj26_kernel(const float* __restrict__ emb,
                              const float* __restrict__ Wih_f, const float* __restrict__ bih_f,
                              const float* __restrict__ bhh_f,
                              const float* __restrict__ Wih_b, const float* __restrict__ bih_b,
                              const float* __restrict__ bhh_b, float* __restrict__ proj) {
    int dir = blockIdx.x, row = blockIdx.y, j = threadIdx.x;
    const float* W = dir ? Wih_b : Wih_f;
    const float* b1 = dir ? bih_b : bih_f;
    const float* b2 = dir ? bhh_b : bhh_f;
    float acc = b1[j] + b2[j];
    const float* e = emb + row * EMB;
    const float* w = W + j * EMB;
    for (int k = 0; k < EMB; ++k) acc += e[k] * w[k];
    proj[(dir * 26 + row) * 256 + j] = acc;
}

__global__ __launch_bounds__(256) void lstm_kernel(const int* __restrict__ target,
                                                   const float* __restrict__ proj26,
                                                   const float* __restrict__ Whh_f,
                                                   const float* __restrict__ Whh_b,
                                                   float* __restrict__ hcat) {
    int n = blockIdx.x;      // 0..999 (sequence position == LSTM batch element)
    int dir = blockIdx.y;    // 0 fwd, 1 bwd
    int tid = threadIdx.x;   // 0..255 (gate unit)
    const float* Whh = dir ? Whh_b : Whh_f;
    const float* proj = proj26 + dir * 26 * 256;
    float w[LH];
#pragma unroll
    for (int u4 = 0; u4 < LH / 4; ++u4) {
        float4 v = *reinterpret_cast<const float4*>(Whh + tid * LH + u4 * 4);
        w[u4 * 4 + 0] = v.x; w[u4 * 4 + 1] = v.y;
        w[u4 * 4 + 2] = v.z; w[u4 * 4 + 3] = v.w;
    }
    __shared__ float h_lds[LH];
    __shared__ float c_lds[LH];
    __shared__ float z_lds[256];
    if (tid < LH) { h_lds[tid] = 0.f; c_lds[tid] = 0.f; }
    __syncthreads();
    for (int s = 0; s < BB; ++s) {
        int t = dir ? (BB - 1 - s) : s;
        int tgt = target[t * SEQ + n];
        float a0 = 0.f, a1 = 0.f, a2 = 0.f, a3 = 0.f;
#pragma unroll
        for (int u = 0; u < LH; u += 4) {
            a0 += w[u] * h_lds[u];
            a1 += w[u + 1] * h_lds[u + 1];
            a2 += w[u + 2] * h_lds[u + 2];
            a3 += w[u + 3] * h_lds[u + 3];
        }
        z_lds[tid] = proj[tgt * 256 + tid] + a0 + a1 + a2 + a3;
        __syncthreads();
        if (tid < LH) {
            float ig = 1.f / (1.f + expf(-z_lds[tid]));
            float fg = 1.f / (1.f + expf(-z_lds[LH + tid]));
            float gg = tanhf(z_lds[2 * LH + tid]);
            float og = 1.f / (1.f + expf(-z_lds[3 * LH + tid]));
            float c = fg * c_lds[tid] + ig * gg;
            float h = og * tanhf(c);
            c_lds[tid] = c;
            h_lds[tid] = h;
            hcat[((size_t)t * SEQ + n) * 128 + dir * LH + tid] = h;
        }
        __syncthreads();
    }
}

__global__ void conv_kernel(const float* __restrict__ hcat, const float* __restrict__ conv_w,
                            const float* __restrict__ conv_b, float* __restrict__ convout) {
    int b = blockIdx.x;   // 64
    int og = blockIdx.y;  // 8 groups of 4 out channels
    int p = threadIdx.x;  // 0..127
    if (p >= 121) return;
    float acc[4] = {0.f, 0.f, 0.f, 0.f};
    for (int i = 0; i < SEQ; ++i) {
        const float* hrow = hcat + ((size_t)b * SEQ + i) * 128;
        float x[8];
#pragma unroll
        for (int k = 0; k < 8; ++k) x[k] = hrow[p + k];
#pragma unroll
        for (int oo = 0; oo < 4; ++oo) {
            const float* wr = conv_w + ((size_t)(og * 4 + oo) * SEQ + i) * 8;
#pragma unroll
            for (int k = 0; k < 8; ++k) acc[oo] += x[k] * wr[k];
        }
    }
#pragma unroll
    for (int oo = 0; oo < 4; ++oo) {
        int o = og * 4 + oo;
        convout[(size_t)b * 3872 + o * 121 + p] = acc[oo] + conv_b[o];
    }
}

// ---------------- launcher ----------------
extern "C" void kernel_launch(void* const* d_in, const int* in_sizes, int n_in,
                              void* d_out, int out_size, void* d_ws, size_t ws_size,
                              hipStream_t stream) {
    const float* x      = (const float*)d_in[0];
    const int*   ei     = (const int*)d_in[1];
    const int*   batch  = (const int*)d_in[2];
    const int*   target = (const int*)d_in[3];
    const float* Wl     = (const float*)d_in[4];
    const float* Wr     = (const float*)d_in[5];
    const float* att    = (const float*)d_in[6];
    const float* gat_b  = (const float*)d_in[7];
    const float* gcn_w  = (const float*)d_in[8];
    const float* gcn_b  = (const float*)d_in[9];
    const float* emb    = (const float*)d_in[10];
    const float* Wih_f  = (const float*)d_in[11];
    const float* Whh_f  = (const float*)d_in[12];
    const float* bih_f  = (const float*)d_in[13];
    const float* bhh_f  = (const float*)d_in[14];
    const float* Wih_b  = (const float*)d_in[15];
    const float* Whh_b  = (const float*)d_in[16];
    const float* bih_b  = (const float*)d_in[17];
    const float* bhh_b  = (const float*)d_in[18];
    const float* conv_w = (const float*)d_in[19];
    const float* conv_b = (const float*)d_in[20];
    const float* fcp_w  = (const float*)d_in[21];
    const float* fcp_b  = (const float*)d_in[22];
    const float* fc1_w  = (const float*)d_in[23];
    const float* fc1_b  = (const float*)d_in[24];
    const float* fc2_w  = (const float*)d_in[25];
    const float* fc2_b  = (const float*)d_in[26];
    const float* out_w  = (const float*)d_in[27];
    const float* out_b  = (const float*)d_in[28];
    float* out = (float*)d_out;
    (void)n_in; (void)in_sizes; (void)out_size;

    // ---------- workspace layout ----------
    char* ws = (char*)d_ws;
    size_t o = 0;
    auto alloc = [&](size_t bytes) {
        char* p = ws + o;
        o = (o + bytes + 255) & ~(size_t)255;
        return p;
    };
    constexpr size_t HALF = (size_t)NN * DD * 2; // 46.8 MB (one bf16 node matrix)
    // Union region (93.6 MB): protein {hcat,proj26,convout} -> {xl_bf|xr_bf} -> {hw_bf|g_bf}
    char* region = (char*)alloc(2 * HALF);
    __hip_bfloat16* xl_bf = (__hip_bfloat16*)region;
    __hip_bfloat16* xr_bf = (__hip_bfloat16*)(region + HALF);
    __hip_bfloat16* hw_bf = (__hip_bfloat16*)region;          // after xl dead
    __hip_bfloat16* g_bf  = (__hip_bfloat16*)(region + HALF); // after xr dead
    float* hcat    = (float*)region;                                      // 32.8 MB
    float* proj26  = (float*)(region + (size_t)BB * SEQ * 128 * 4 + 256); // 53 KB
    float* convout = (float*)((char*)proj26 + 2 * 26 * 256 * 4 + 256);    // 1 MB
    // Persistent buffers
    __hip_bfloat16* h_bf  = (__hip_bfloat16*)alloc(HALF);
    __hip_bfloat16* x_bf  = (__hip_bfloat16*)alloc((size_t)NN * CC * 2);
    __hip_bfloat16* wl_t  = (__hip_bfloat16*)alloc((size_t)DD * CC * 2);
    __hip_bfloat16* wr_t  = (__hip_bfloat16*)alloc((size_t)DD * CC * 2);
    __hip_bfloat16* gcw_t = (__hip_bfloat16*)alloc((size_t)DD * DD * 2);
    float* fcp_wt = (float*)alloc((size_t)3872 * 128 * 4);
    float* fc1_wt = (float*)alloc((size_t)COMBD * 1024 * 4);
    float* fc2_wt = (float*)alloc((size_t)1024 * 512 * 4);
    float* out_wt = (float*)alloc((size_t)512 * 4);
    float* logit    = (float*)alloc((size_t)ET * HH * 4); // logits -> alpha in place
    int*   csr_src  = (int*)alloc((size_t)ET * 4);
    int*   csr_dst  = (int*)alloc((size_t)ET * 4);
    int*   deg      = (int*)alloc((size_t)NN * 4);
    int*   cursor   = (int*)alloc((size_t)NN * 4);
    int*   offs     = (int*)alloc((size_t)(NN + 1) * 4);
    float* dinv     = (float*)alloc((size_t)NN * 4);
    int*   gstart   = (int*)alloc(64 * 4);
    int*   gend     = (int*)alloc(64 * 4);
    float* pmax     = (float*)alloc((size_t)BB * DD * 4);
    float* psum     = (float*)alloc((size_t)BB * DD * 4);
    float* comb     = (float*)alloc((size_t)BB * COMBD * 4);
    float* h1       = (float*)alloc((size_t)BB * 1024 * 4);
    float* h2       = (float*)alloc((size_t)BB * 512 * 4);
    if (o > ws_size) return;  // diagnostic: insufficient workspace -> no launches

    // zero scratch that is accumulated into
    hipMemsetAsync(deg, 0, (size_t)NN * 4, stream);
    hipMemsetAsync(cursor, 0, (size_t)NN * 4, stream);
    hipMemsetAsync(gstart, 0, 64 * 4, stream);
    hipMemsetAsync(gend, 0, 64 * 4, stream);
    hipMemsetAsync(pmax, 0, (size_t)BB * DD * 4, stream);
    hipMemsetAsync(psum, 0, (size_t)BB * DD * 4, stream);

    // ---------- protein branch (uses the union region first) ----------
    {
        dim3 grid(2, 26);
        proj26_kernel<<<grid, 256, 0, stream>>>(emb, Wih_f, bih_f, bhh_f, Wih_b, bih_b, bhh_b, proj26);
    }
    {
        dim3 grid(SEQ, 2);
        lstm_kernel<<<grid, 256, 0, stream>>>(target, proj26, Whh_f, Whh_b, hcat);
    }
    {
        dim3 grid(BB, 8);
        conv_kernel<<<grid, 128, 0, stream>>>(hcat, conv_w, conv_b, convout);
    }
    transpose_f32<<<(3872 * 128 + 255) / 256, 256, 0, stream>>>(fcp_w, fcp_wt, 3872, 128);
    gemm_skinny<0><<<(BB * 128 + 3) / 4, 256, 0, stream>>>(convout, fcp_wt, fcp_b,
                                                           comb + 2 * DD, BB, 128, 3872, COMBD);

    // ---------- conversions / transposes ----------
    f32_to_bf16<<<(NN * CC + 255) / 256, 256, 0, stream>>>(x, x_bf, NN * CC);
    transpose_to_bf16<<<(CC * DD + 255) / 256, 256, 0, stream>>>(Wl, wl_t, CC, DD);
    transpose_to_bf16<<<(CC * DD + 255) / 256, 256, 0, stream>>>(Wr, wr_t, CC, DD);
    transpose_to_bf16<<<(DD * DD + 255) / 256, 256, 0, stream>>>(gcn_w, gcw_t, DD, DD);
    transpose_f32<<<(COMBD * 1024 + 255) / 256, 256, 0, stream>>>(fc1_w, fc1_wt, COMBD, 1024);
    transpose_f32<<<(1024 * 512 + 255) / 256, 256, 0, stream>>>(fc2_w, fc2_wt, 1024, 512);
    transpose_f32<<<(512 + 255) / 256, 256, 0, stream>>>(out_w, out_wt, 512, 1);

    // ---------- graph branch ----------
    dim3 ggrid((DD + 127) / 128, (NN + 127) / 128);
    gemm_bf16_mfma<1><<<ggrid, 256, 0, stream>>>(x_bf, wl_t, xl_bf, NN, DD, CC);
    gemm_bf16_mfma<1><<<ggrid, 256, 0, stream>>>(x_bf, wr_t, xr_bf, NN, DD, CC);
    // CSR
    deg_count<<<(ET + 255) / 256, 256, 0, stream>>>(ei, deg);
    scan_kernel<<<1, 1024, 0, stream>>>(deg, offs);
    csr_fill<<<(ET + 255) / 256, 256, 0, stream>>>(ei, offs, cursor, csr_src, csr_dst);
    dinv_kernel<<<(NN + 255) / 256, 256, 0, stream>>>(deg, dinv);
    // GATv2
    gat_logits<<<(ET * HH + 255) / 256, 256, 0, stream>>>((const unsigned short*)xl_bf,
                                                          (const unsigned short*)xr_bf,
                                                          att, csr_src, csr_dst, logit);
    gat_softmax<<<(NN * HH + 255) / 256, 256, 0, stream>>>(offs, logit);
    gat_aggregate<<<NN, 256, 0, stream>>>(offs, csr_src, logit,
                                          (const unsigned short*)xl_bf, gat_b, h_bf);
    // GCN: hw = h @ gcn_w^T (bf16 out, overwrites dead xl); aggregate -> g_bf (dead xr)
    gemm_bf16_mfma<1><<<ggrid, 256, 0, stream>>>(h_bf, gcw_t, hw_bf, NN, DD, DD);
    gcn_aggregate<<<NN, 256, 0, stream>>>(offs, csr_src, dinv,
                                          (const unsigned short*)hw_bf, gcn_b, g_bf);
    // pooling -> comb[:, 0:1560]
    graph_ranges<<<(NN + 255) / 256, 256, 0, stream>>>(batch, gstart, gend);
    pool_partial<<<(NN + PCHUNK - 1) / PCHUNK, 256, 0, stream>>>((const unsigned short*)g_bf,
                                                                 batch, pmax, psum);
    pool_finalize<<<(BB * DD + 255) / 256, 256, 0, stream>>>(pmax, psum, gstart, gend, comb);

    // ---------- combined head ----------
    gemm_skinny<1><<<(BB * 1024 + 3) / 4, 256, 0, stream>>>(comb, fc1_wt, fc1_b, h1,
                                                            BB, 1024, COMBD, 1024);
    gemm_skinny<1><<<(BB * 512 + 3) / 4, 256, 0, stream>>>(h1, fc2_wt, fc2_b, h2,
                                                           BB, 512, 1024, 512);
    gemm_skinny<0><<<(BB + 3) / 4, 256, 0, stream>>>(h2, out_wt, out_b, out,
                                                     BB, 1, 512, 1);
}

// Round 6
// 1008.906 us; speedup vs baseline: 3.7904x; 1.2459x over previous
//
#include <hip/hip_runtime.h>
#include <hip/hip_bf16.h>
#include <math.h>

// Problem constants (fixed by setup_inputs)
static constexpr int NN   = 30000;   // nodes
static constexpr int EE   = 240000;  // edges (before self loops)
static constexpr int ET   = EE + NN; // edges incl self loops
static constexpr int BB   = 64;      // graphs
static constexpr int HH   = 10;      // heads
static constexpr int CC   = 78;      // per-head dim
static constexpr int DD   = HH * CC; // 780
static constexpr int SEQ  = 1000;
static constexpr int EMB  = 128;
static constexpr int LH   = 64;
static constexpr int COMBD = 2 * DD + 128; // 1688
static constexpr int PCHUNK = 64;    // nodes per pool_partial block

typedef __attribute__((ext_vector_type(8))) short short8;
typedef __attribute__((ext_vector_type(4))) float f32x4;

__device__ __forceinline__ float bf2f(unsigned short u) {
    return __uint_as_float(((unsigned int)u) << 16);
}

// ---------------- bf16 MFMA GEMM: C[M,N] = A[M,K] @ Bt[N,K]^T ----------------
// OBF=1 -> C stored as bf16, else f32. f32 accumulation via MFMA.
template <int OBF>
__global__ __launch_bounds__(256) void gemm_bf16_mfma(const __hip_bfloat16* __restrict__ A,
                                                      const __hip_bfloat16* __restrict__ Bt,
                                                      void* __restrict__ Cv,
                                                      int M, int N, int K) {
    constexpr int LDS_S = 40;
    __shared__ unsigned short As[128 * LDS_S];
    __shared__ unsigned short Bs[128 * LDS_S];
    const int tid  = threadIdx.x;
    const int lane = tid & 63, wid = tid >> 6;
    const int wr = wid >> 1, wc = wid & 1;
    const int l15 = lane & 15, l4 = lane >> 4;
    const int bm = blockIdx.y * 128, bn = blockIdx.x * 128;
    const int tr = tid >> 2, tc = (tid & 3) * 8;

    const unsigned short* Au = (const unsigned short*)A;
    const unsigned short* Bu = (const unsigned short*)Bt;

    f32x4 acc[4][4];
#pragma unroll
    for (int m = 0; m < 4; ++m)
#pragma unroll
        for (int n = 0; n < 4; ++n) acc[m][n] = (f32x4){0.f, 0.f, 0.f, 0.f};

    for (int k0 = 0; k0 < K; k0 += 32) {
#pragma unroll
        for (int half = 0; half < 2; ++half) {
            int row = tr + half * 64;
            { // A tile
                int grow = bm + row;
                short8 sv;
                if (grow < M && k0 + tc + 8 <= K) {
                    const unsigned int* p = (const unsigned int*)(Au + (size_t)grow * K + k0 + tc);
#pragma unroll
                    for (int j = 0; j < 4; ++j) {
                        unsigned int u = p[j];
                        sv[2 * j]     = (short)(u & 0xffffu);
                        sv[2 * j + 1] = (short)(u >> 16);
                    }
                } else {
#pragma unroll
                    for (int j = 0; j < 8; ++j) {
                        int gk = k0 + tc + j;
                        sv[j] = (grow < M && gk < K) ? (short)Au[(size_t)grow * K + gk] : (short)0;
                    }
                }
                *reinterpret_cast<short8*>(&As[row * LDS_S + tc]) = sv;
            }
            { // B^T tile
                int grow = bn + row;
                short8 sv;
                if (grow < N && k0 + tc + 8 <= K) {
                    const unsigned int* p = (const unsigned int*)(Bu + (size_t)grow * K + k0 + tc);
#pragma unroll
                    for (int j = 0; j < 4; ++j) {
                        unsigned int u = p[j];
                        sv[2 * j]     = (short)(u & 0xffffu);
                        sv[2 * j + 1] = (short)(u >> 16);
                    }
                } else {
#pragma unroll
                    for (int j = 0; j < 8; ++j) {
                        int gk = k0 + tc + j;
                        sv[j] = (grow < N && gk < K) ? (short)Bu[(size_t)grow * K + gk] : (short)0;
                    }
                }
                *reinterpret_cast<short8*>(&Bs[row * LDS_S + tc]) = sv;
            }
        }
        __syncthreads();
        short8 a[4], b[4];
#pragma unroll
        for (int m = 0; m < 4; ++m)
            a[m] = *reinterpret_cast<const short8*>(&As[(wr * 64 + m * 16 + l15) * LDS_S + l4 * 8]);
#pragma unroll
        for (int n = 0; n < 4; ++n)
            b[n] = *reinterpret_cast<const short8*>(&Bs[(wc * 64 + n * 16 + l15) * LDS_S + l4 * 8]);
#pragma unroll
        for (int m = 0; m < 4; ++m)
#pragma unroll
            for (int n = 0; n < 4; ++n)
                acc[m][n] = __builtin_amdgcn_mfma_f32_16x16x32_bf16(a[m], b[n], acc[m][n], 0, 0, 0);
        __syncthreads();
    }
#pragma unroll
    for (int m = 0; m < 4; ++m)
#pragma unroll
        for (int n = 0; n < 4; ++n)
#pragma unroll
            for (int r = 0; r < 4; ++r) {
                int row = bm + wr * 64 + m * 16 + l4 * 4 + r;
                int col = bn + wc * 64 + n * 16 + l15;
                if (row < M && col < N) {
                    if (OBF)
                        ((__hip_bfloat16*)Cv)[(size_t)row * N + col] = __float2bfloat16(acc[m][n][r]);
                    else
                        ((float*)Cv)[(size_t)row * N + col] = acc[m][n][r];
                }
            }
}

// ---------------- conversions ----------------
__global__ void f32_to_bf16(const float* __restrict__ in, __hip_bfloat16* __restrict__ out, int n) {
    int i = blockIdx.x * blockDim.x + threadIdx.x;
    if (i < n) out[i] = __float2bfloat16(in[i]);
}

// in[K][N] f32 -> out[N][K] bf16
__global__ void transpose_to_bf16(const float* __restrict__ in, __hip_bfloat16* __restrict__ out,
                                  int Kdim, int Ndim) {
    int idx = blockIdx.x * blockDim.x + threadIdx.x;
    if (idx >= Kdim * Ndim) return;
    int n = idx / Kdim, k = idx % Kdim;
    out[idx] = __float2bfloat16(in[(size_t)k * Ndim + n]);
}

// in[K][N] f32 -> out[N][K] f32
__global__ void transpose_f32(const float* __restrict__ in, float* __restrict__ out,
                              int Kdim, int Ndim) {
    int idx = blockIdx.x * blockDim.x + threadIdx.x;
    if (idx >= Kdim * Ndim) return;
    int n = idx / Kdim, k = idx % Kdim;
    out[idx] = in[(size_t)k * Ndim + n];
}

// ------------- skinny GEMM: wave-per-output split-K. Bt is [N][K]. -------------
template <int ACT>
__global__ __launch_bounds__(256) void gemm_skinny(const float* __restrict__ A,
                                                   const float* __restrict__ Bt,
                                                   const float* __restrict__ bias,
                                                   float* __restrict__ C,
                                                   int M, int N, int K, int ldc) {
    int oidx = blockIdx.x * 4 + (threadIdx.x >> 6);
    int lane = threadIdx.x & 63;
    if (oidx >= M * N) return;
    int row = oidx / N, col = oidx % N;
    const float4* a = (const float4*)(A + (size_t)row * K);
    const float4* b = (const float4*)(Bt + (size_t)col * K);
    int K4 = K >> 2;
    float s = 0.f;
    for (int i = lane; i < K4; i += 64) {
        float4 x = a[i], y = b[i];
        s += x.x * y.x + x.y * y.y + x.z * y.z + x.w * y.w;
    }
#pragma unroll
    for (int off = 32; off; off >>= 1) s += __shfl_xor(s, off);
    if (lane == 0) {
        s += bias[col];
        if (ACT == 1) s = fmaxf(s, 0.f);
        C[(size_t)row * ldc + col] = s;
    }
}

// ---------------- CSR construction ----------------
__global__ void deg_count(const int* __restrict__ ei, int* __restrict__ deg) {
    int e = blockIdx.x * blockDim.x + threadIdx.x;
    if (e >= ET) return;
    int d = (e < EE) ? ei[EE + e] : (e - EE);
    atomicAdd(&deg[d], 1);
}

__global__ __launch_bounds__(1024) void scan_kernel(const int* __restrict__ deg,
                                                    int* __restrict__ offs) {
    __shared__ int lds[1024];
    int tid = threadIdx.x;
    const int chunk = (NN + 1023) / 1024;
    int base = tid * chunk;
    int s = 0;
    for (int i = 0; i < chunk; ++i) {
        int idx = base + i;
        if (idx < NN) s += deg[idx];
    }
    lds[tid] = s;
    __syncthreads();
    for (int d = 1; d < 1024; d <<= 1) {
        int v = (tid >= d) ? lds[tid - d] : 0;
        __syncthreads();
        lds[tid] += v;
        __syncthreads();
    }
    int run = (tid == 0) ? 0 : lds[tid - 1];
    for (int i = 0; i < chunk; ++i) {
        int idx = base + i;
        if (idx < NN) { offs[idx] = run; run += deg[idx]; }
    }
    if (tid == 1023) offs[NN] = lds[1023];
}

__global__ void csr_fill(const int* __restrict__ ei, const int* __restrict__ offs,
                         int* __restrict__ cursor, int* __restrict__ csr_src,
                         int* __restrict__ csr_dst) {
    int e = blockIdx.x * blockDim.x + threadIdx.x;
    if (e >= ET) return;
    int s = (e < EE) ? ei[e] : (e - EE);
    int d = (e < EE) ? ei[EE + e] : (e - EE);
    int pos = atomicAdd(&cursor[d], 1);
    int slot = offs[d] + pos;
    csr_src[slot] = s;
    csr_dst[slot] = d;
}

__global__ void dinv_kernel(const int* __restrict__ deg, float* __restrict__ dinv) {
    int n = blockIdx.x * blockDim.x + threadIdx.x;
    if (n >= NN) return;
    float dg = (float)deg[n];
    dinv[n] = (dg > 0.f) ? 1.f / sqrtf(dg) : 0.f;
}

// ---------------- GATv2 (bf16 gathers, f32 accumulation) ----------------
__global__ void gat_logits(const unsigned short* __restrict__ xl,
                           const unsigned short* __restrict__ xr,
                           const float* __restrict__ att, const int* __restrict__ csr_src,
                           const int* __restrict__ csr_dst, float* __restrict__ logit) {
    int idx = blockIdx.x * blockDim.x + threadIdx.x;
    if (idx >= ET * HH) return;
    int i = idx / HH, h = idx % HH;
    int s = csr_src[i], d = csr_dst[i];
    const unsigned int* pl = (const unsigned int*)(xl + (size_t)s * DD + h * CC);
    const unsigned int* pr = (const unsigned int*)(xr + (size_t)d * DD + h * CC);
    const float* pa = att + h * CC;
    float acc = 0.f;
#pragma unroll
    for (int c = 0; c < CC / 2; ++c) {
        unsigned int a = pl[c], b = pr[c];
        float v0 = __uint_as_float((a & 0xffffu) << 16) + __uint_as_float((b & 0xffffu) << 16);
        float v1 = __uint_as_float(a & 0xffff0000u) + __uint_as_float(b & 0xffff0000u);
        v0 = (v0 > 0.f) ? v0 : 0.2f * v0;
        v1 = (v1 > 0.f) ? v1 : 0.2f * v1;
        acc += pa[2 * c] * v0 + pa[2 * c + 1] * v1;
    }
    logit[idx] = acc;
}

__global__ void gat_softmax(const int* __restrict__ offs, float* __restrict__ logit) {
    int idx = blockIdx.x * blockDim.x + threadIdx.x;
    if (idx >= NN * HH) return;
    int n = idx / HH, h = idx % HH;
    int i0 = offs[n], i1 = offs[n + 1];
    float m = -1e30f;
    for (int i = i0; i < i1; ++i) m = fmaxf(m, logit[i * HH + h]);
    float den = 0.f;
    for (int i = i0; i < i1; ++i) {
        float e = expf(logit[i * HH + h] - m);
        logit[i * HH + h] = e;
        den += e;
    }
    float inv = 1.f / den;
    for (int i = i0; i < i1; ++i) logit[i * HH + h] *= inv;
}

// reads bf16 xl, writes bf16 h
__global__ __launch_bounds__(256) void gat_aggregate(const int* __restrict__ offs,
                                                     const int* __restrict__ csr_src,
                                                     const float* __restrict__ alpha,
                                                     const unsigned short* __restrict__ xl,
                                                     const float* __restrict__ gat_b,
                                                     __hip_bfloat16* __restrict__ hout) {
    int n = blockIdx.x;
    int tid = threadIdx.x;
    int i0 = offs[n], i1 = offs[n + 1];
    int d0 = tid, d1 = tid + 256, d2 = tid + 512, d3 = tid + 768;
    int h0 = d0 / CC, h1 = d1 / CC, h2 = d2 / CC, h3 = (d3 < DD) ? d3 / CC : 0;
    float a0 = 0.f, a1 = 0.f, a2 = 0.f, a3 = 0.f;
    for (int i = i0; i < i1; ++i) {
        const unsigned short* row = xl + (size_t)csr_src[i] * DD;
        const float* al = alpha + (size_t)i * HH;
        a0 += al[h0] * bf2f(row[d0]);
        a1 += al[h1] * bf2f(row[d1]);
        a2 += al[h2] * bf2f(row[d2]);
        if (d3 < DD) a3 += al[h3] * bf2f(row[d3]);
    }
    float v;
    v = a0 + gat_b[d0]; v = (v > 0.f) ? v : expf(v) - 1.f;
    hout[(size_t)n * DD + d0] = __float2bfloat16(v);
    v = a1 + gat_b[d1]; v = (v > 0.f) ? v : expf(v) - 1.f;
    hout[(size_t)n * DD + d1] = __float2bfloat16(v);
    v = a2 + gat_b[d2]; v = (v > 0.f) ? v : expf(v) - 1.f;
    hout[(size_t)n * DD + d2] = __float2bfloat16(v);
    if (d3 < DD) {
        v = a3 + gat_b[d3]; v = (v > 0.f) ? v : expf(v) - 1.f;
        hout[(size_t)n * DD + d3] = __float2bfloat16(v);
    }
}

// ---------------- GCN aggregation (bf16 in, bf16 out) ----------------
__global__ __launch_bounds__(256) void gcn_aggregate(const int* __restrict__ offs,
                                                     const int* __restrict__ csr_src,
                                                     const float* __restrict__ dinv,
                                                     const unsigned short* __restrict__ hw,
                                                     const float* __restrict__ gcn_b,
                                                     __hip_bfloat16* __restrict__ g) {
    int n = blockIdx.x;
    int tid = threadIdx.x;
    float din = dinv[n];
    int i0 = offs[n], i1 = offs[n + 1];
    int d0 = tid, d1 = tid + 256, d2 = tid + 512, d3 = tid + 768;
    float a0 = 0.f, a1 = 0.f, a2 = 0.f, a3 = 0.f;
    for (int i = i0; i < i1; ++i) {
        int s = csr_src[i];
        float w = dinv[s] * din;
        const unsigned short* row = hw + (size_t)s * DD;
        a0 += w * bf2f(row[d0]);
        a1 += w * bf2f(row[d1]);
        a2 += w * bf2f(row[d2]);
        if (d3 < DD) a3 += w * bf2f(row[d3]);
    }
    g[(size_t)n * DD + d0] = __float2bfloat16(fmaxf(a0 + gcn_b[d0], 0.f));
    g[(size_t)n * DD + d1] = __float2bfloat16(fmaxf(a1 + gcn_b[d1], 0.f));
    g[(size_t)n * DD + d2] = __float2bfloat16(fmaxf(a2 + gcn_b[d2], 0.f));
    if (d3 < DD) g[(size_t)n * DD + d3] = __float2bfloat16(fmaxf(a3 + gcn_b[d3], 0.f));
}

// ---------------- pooling ----------------
__global__ void graph_ranges(const int* __restrict__ batch, int* __restrict__ gstart,
                             int* __restrict__ gend) {
    int n = blockIdx.x * blockDim.x + threadIdx.x;
    if (n >= NN) return;
    int b = batch[n];
    if (n == 0 || batch[n - 1] != b) gstart[b] = n;
    if (n == NN - 1 || batch[n + 1] != b) gend[b] = n + 1;
}

// stage 1: chunk-of-nodes per block, coalesced bf16 row reads, atomic merge at
// sorted-batch boundaries. g >= 0 (ReLU): atomicMax on uint bits exact, zero-init ok.
__global__ __launch_bounds__(256) void pool_partial(const unsigned short* __restrict__ g,
                                                    const int* __restrict__ batch,
                                                    float* __restrict__ pmax,
                                                    float* __restrict__ psum) {
    int chunk0 = blockIdx.x * PCHUNK;
    int tid = threadIdx.x;
    __shared__ int bsh[PCHUNK];
    for (int i = tid; i < PCHUNK; i += 256) {
        int n = chunk0 + i;
        bsh[i] = (n < NN) ? batch[n] : -1;
    }
    __syncthreads();
    float mx[4] = {0.f, 0.f, 0.f, 0.f};
    float sm[4] = {0.f, 0.f, 0.f, 0.f};
    int curb = bsh[0];
    auto flush = [&](int b) {
#pragma unroll
        for (int j = 0; j < 4; ++j) {
            int d = tid + j * 256;
            if (d < DD && b >= 0) {
                atomicMax((unsigned int*)&pmax[(size_t)b * DD + d], __float_as_uint(mx[j]));
                atomicAdd(&psum[(size_t)b * DD + d], sm[j]);
            }
            mx[j] = 0.f; sm[j] = 0.f;
        }
    };
    for (int i = 0; i < PCHUNK; ++i) {
        int n = chunk0 + i;
        if (n >= NN) break;
        int b = bsh[i];
        if (b != curb) { flush(curb); curb = b; }
        const unsigned short* row = g + (size_t)n * DD;
#pragma unroll
        for (int j = 0; j < 4; ++j) {
            int d = tid + j * 256;
            if (d < DD) {
                float v = bf2f(row[d]);
                mx[j] = fmaxf(mx[j], v);
                sm[j] += v;
            }
        }
    }
    flush(curb);
}

// stage 2: write comb layout
__global__ void pool_finalize(const float* __restrict__ pmax, const float* __restrict__ psum,
                              const int* __restrict__ gstart, const int* __restrict__ gend,
                              float* __restrict__ comb) {
    int idx = blockIdx.x * blockDim.x + threadIdx.x;
    if (idx >= BB * DD) return;
    int b = idx / DD, d = idx % DD;
    float cnt = fmaxf((float)(gend[b] - gstart[b]), 1.f);
    comb[(size_t)b * COMBD + d] = pmax[idx];
    comb[(size_t)b * COMBD + DD + d] = psum[idx] / cnt;
}

// ---------------- protein branch ----------------
__global__ void proj26_kernel(const float* __restrict__ emb,
                              const float* __restrict__ Wih_f, const float* __restrict__ bih_f,
                              const float* __restrict__ bhh_f,
                              const float* __restrict__ Wih_b, const float* __restrict__ bih_b,
                              const float* __restrict__ bhh_b, float* __restrict__ proj) {
    int dir = blockIdx.x, row = blockIdx.y, j = threadIdx.x;
    const float* W = dir ? Wih_b : Wih_f;
    const float* b1 = dir ? bih_b : bih_f;
    const float* b2 = dir ? bhh_b : bhh_f;
    float acc = b1[j] + b2[j];
    const float* e = emb + row * EMB;
    const float* w = W + j * EMB;
    for (int k = 0; k < EMB; ++k) acc += e[k] * w[k];
    proj[(dir * 26 + row) * 256 + j] = acc;
}

__global__ __launch_bounds__(256) void lstm_kernel(const int* __restrict__ target,
                                                   const float* __restrict__ proj26,
                                                   const float* __restrict__ Whh_f,
                                                   const float* __restrict__ Whh_b,
                                                   float* __restrict__ hcat) {
    int n = blockIdx.x;      // 0..999 (sequence position == LSTM batch element)
    int dir = blockIdx.y;    // 0 fwd, 1 bwd
    int tid = threadIdx.x;   // 0..255 (gate unit)
    const float* Whh = dir ? Whh_b : Whh_f;
    const float* proj = proj26 + dir * 26 * 256;
    float w[LH];
#pragma unroll
    for (int u4 = 0; u4 < LH / 4; ++u4) {
        float4 v = *reinterpret_cast<const float4*>(Whh + tid * LH + u4 * 4);
        w[u4 * 4 + 0] = v.x; w[u4 * 4 + 1] = v.y;
        w[u4 * 4 + 2] = v.z; w[u4 * 4 + 3] = v.w;
    }
    __shared__ float h_lds[LH];
    __shared__ float c_lds[LH];
    __shared__ float z_lds[256];
    if (tid < LH) { h_lds[tid] = 0.f; c_lds[tid] = 0.f; }
    __syncthreads();
    for (int s = 0; s < BB; ++s) {
        int t = dir ? (BB - 1 - s) : s;
        int tgt = target[t * SEQ + n];
        float a0 = 0.f, a1 = 0.f, a2 = 0.f, a3 = 0.f;
#pragma unroll
        for (int u = 0; u < LH; u += 4) {
            a0 += w[u] * h_lds[u];
            a1 += w[u + 1] * h_lds[u + 1];
            a2 += w[u + 2] * h_lds[u + 2];
            a3 += w[u + 3] * h_lds[u + 3];
        }
        z_lds[tid] = proj[tgt * 256 + tid] + a0 + a1 + a2 + a3;
        __syncthreads();
        if (tid < LH) {
            float ig = 1.f / (1.f + expf(-z_lds[tid]));
            float fg = 1.f / (1.f + expf(-z_lds[LH + tid]));
            float gg = tanhf(z_lds[2 * LH + tid]);
            float og = 1.f / (1.f + expf(-z_lds[3 * LH + tid]));
            float c = fg * c_lds[tid] + ig * gg;
            float h = og * tanhf(c);
            c_lds[tid] = c;
            h_lds[tid] = h;
            hcat[((size_t)t * SEQ + n) * 128 + dir * LH + tid] = h;
        }
        __syncthreads();
    }
}

// hcat[b][i][h] f32 -> hcatT[b][h][i] bf16 (LDS tiled transpose)
__global__ __launch_bounds__(256) void transpose_hcat(const float* __restrict__ hcat,
                                                      unsigned short* __restrict__ hcatT) {
    int b = blockIdx.z;
    int i0 = blockIdx.y * 32;
    int h0 = blockIdx.x * 32;
    int th = threadIdx.x & 31;     // fast dim on read
    int ti = threadIdx.x >> 5;     // 0..7
    __shared__ float t[32][33];
#pragma unroll
    for (int r = 0; r < 4; ++r) {
        int i = i0 + ti + r * 8;
        if (i < SEQ) t[ti + r * 8][th] = hcat[((size_t)b * SEQ + i) * 128 + h0 + th];
    }
    __syncthreads();
#pragma unroll
    for (int r = 0; r < 4; ++r) {
        int h = h0 + ti + r * 8;
        int i = i0 + th;
        if (i < SEQ) {
            unsigned int u = __float_as_uint(t[th][ti + r * 8]);
            // round-to-nearest-even bf16
            unsigned int lsb = (u >> 16) & 1u;
            u += 0x7fffu + lsb;
            hcatT[((size_t)b * 128 + h) * SEQ + i] = (unsigned short)(u >> 16);
        }
    }
}

// conv_w[o][i][k] f32 -> wT[o*8+k][i] bf16
__global__ void reshape_convw(const float* __restrict__ conv_w, __hip_bfloat16* __restrict__ wT) {
    int idx = blockIdx.x * blockDim.x + threadIdx.x;
    if (idx >= 256 * SEQ) return;
    int np = idx / SEQ, i = idx % SEQ;
    int o = np >> 3, k = np & 7;
    wT[idx] = __float2bfloat16(conv_w[((size_t)o * SEQ + i) * 8 + k]);
}

// out[b][o][p] = sum_k T[(b*128+p+k)][o*8+k] + conv_b[o]
__global__ void conv_finalize(const float* __restrict__ T, const float* __restrict__ conv_b,
                              float* __restrict__ convout) {
    int idx = blockIdx.x * blockDim.x + threadIdx.x;
    if (idx >= BB * 32 * 121) return;
    int p = idx % 121;
    int o = (idx / 121) % 32;
    int b = idx / (121 * 32);
    float acc = conv_b[o];
#pragma unroll
    for (int k = 0; k < 8; ++k)
        acc += T[(size_t)(b * 128 + p + k) * 256 + o * 8 + k];
    convout[(size_t)b * 3872 + o * 121 + p] = acc;
}

// ---------------- launcher ----------------
extern "C" void kernel_launch(void* const* d_in, const int* in_sizes, int n_in,
                              void* d_out, int out_size, void* d_ws, size_t ws_size,
                              hipStream_t stream) {
    const float* x      = (const float*)d_in[0];
    const int*   ei     = (const int*)d_in[1];
    const int*   batch  = (const int*)d_in[2];
    const int*   target = (const int*)d_in[3];
    const float* Wl     = (const float*)d_in[4];
    const float* Wr     = (const float*)d_in[5];
    const float* att    = (const float*)d_in[6];
    const float* gat_b  = (const float*)d_in[7];
    const float* gcn_w  = (const float*)d_in[8];
    const float* gcn_b  = (const float*)d_in[9];
    const float* emb    = (const float*)d_in[10];
    const float* Wih_f  = (const float*)d_in[11];
    const float* Whh_f  = (const float*)d_in[12];
    const float* bih_f  = (const float*)d_in[13];
    const float* bhh_f  = (const float*)d_in[14];
    const float* Wih_b  = (const float*)d_in[15];
    const float* Whh_b  = (const float*)d_in[16];
    const float* bih_b  = (const float*)d_in[17];
    const float* bhh_b  = (const float*)d_in[18];
    const float* conv_w = (const float*)d_in[19];
    const float* conv_b = (const float*)d_in[20];
    const float* fcp_w  = (const float*)d_in[21];
    const float* fcp_b  = (const float*)d_in[22];
    const float* fc1_w  = (const float*)d_in[23];
    const float* fc1_b  = (const float*)d_in[24];
    const float* fc2_w  = (const float*)d_in[25];
    const float* fc2_b  = (const float*)d_in[26];
    const float* out_w  = (const float*)d_in[27];
    const float* out_b  = (const float*)d_in[28];
    float* out = (float*)d_out;
    (void)n_in; (void)in_sizes; (void)out_size;

    // ---------- workspace layout ----------
    char* ws = (char*)d_ws;
    size_t o = 0;
    auto alloc = [&](size_t bytes) {
        char* p = ws + o;
        o = (o + bytes + 255) & ~(size_t)255;
        return p;
    };
    constexpr size_t HALF = (size_t)NN * DD * 2; // 46.8 MB (one bf16 node matrix)
    // Union region (93.6 MB): protein {hcat,proj26,convout,wT,hcatT,T} -> {xl_bf|xr_bf} -> {hw_bf|g_bf}
    char* region = (char*)alloc(2 * HALF);
    __hip_bfloat16* xl_bf = (__hip_bfloat16*)region;
    __hip_bfloat16* xr_bf = (__hip_bfloat16*)(region + HALF);
    __hip_bfloat16* hw_bf = (__hip_bfloat16*)region;          // after xl dead
    __hip_bfloat16* g_bf  = (__hip_bfloat16*)(region + HALF); // after xr dead
    // protein-phase sub-layout inside the union region
    char* rp = region;
    auto palloc = [&](size_t bytes) {
        char* p = rp;
        rp += (bytes + 255) & ~(size_t)255;
        return p;
    };
    float* hcat    = (float*)palloc((size_t)BB * SEQ * 128 * 4);   // 32.8 MB
    float* proj26  = (float*)palloc(2 * 26 * 256 * 4);             // 53 KB
    float* convout = (float*)palloc((size_t)BB * 3872 * 4);        // 1 MB
    __hip_bfloat16* wT = (__hip_bfloat16*)palloc((size_t)256 * SEQ * 2);        // 0.5 MB
    unsigned short* hcatT = (unsigned short*)palloc((size_t)BB * 128 * SEQ * 2); // 16.4 MB
    float* T = (float*)palloc((size_t)BB * 128 * 256 * 4);         // 8.4 MB  (< 93.6 total)
    // Persistent buffers
    __hip_bfloat16* h_bf  = (__hip_bfloat16*)alloc(HALF);
    __hip_bfloat16* x_bf  = (__hip_bfloat16*)alloc((size_t)NN * CC * 2);
    __hip_bfloat16* wl_t  = (__hip_bfloat16*)alloc((size_t)DD * CC * 2);
    __hip_bfloat16* wr_t  = (__hip_bfloat16*)alloc((size_t)DD * CC * 2);
    __hip_bfloat16* gcw_t = (__hip_bfloat16*)alloc((size_t)DD * DD * 2);
    float* fcp_wt = (float*)alloc((size_t)3872 * 128 * 4);
    float* fc1_wt = (float*)alloc((size_t)COMBD * 1024 * 4);
    float* fc2_wt = (float*)alloc((size_t)1024 * 512 * 4);
    float* out_wt = (float*)alloc((size_t)512 * 4);
    float* logit    = (float*)alloc((size_t)ET * HH * 4); // logits -> alpha in place
    int*   csr_src  = (int*)alloc((size_t)ET * 4);
    int*   csr_dst  = (int*)alloc((size_t)ET * 4);
    int*   deg      = (int*)alloc((size_t)NN * 4);
    int*   cursor   = (int*)alloc((size_t)NN * 4);
    int*   offs     = (int*)alloc((size_t)(NN + 1) * 4);
    float* dinv     = (float*)alloc((size_t)NN * 4);
    int*   gstart   = (int*)alloc(64 * 4);
    int*   gend     = (int*)alloc(64 * 4);
    float* pmax     = (float*)alloc((size_t)BB * DD * 4);
    float* psum     = (float*)alloc((size_t)BB * DD * 4);
    float* comb     = (float*)alloc((size_t)BB * COMBD * 4);
    float* h1       = (float*)alloc((size_t)BB * 1024 * 4);
    float* h2       = (float*)alloc((size_t)BB * 512 * 4);
    if (o > ws_size) return;  // diagnostic: insufficient workspace -> no launches

    // zero scratch that is accumulated into
    hipMemsetAsync(deg, 0, (size_t)NN * 4, stream);
    hipMemsetAsync(cursor, 0, (size_t)NN * 4, stream);
    hipMemsetAsync(gstart, 0, 64 * 4, stream);
    hipMemsetAsync(gend, 0, 64 * 4, stream);
    hipMemsetAsync(pmax, 0, (size_t)BB * DD * 4, stream);
    hipMemsetAsync(psum, 0, (size_t)BB * DD * 4, stream);

    // ---------- protein branch (uses the union region first) ----------
    {
        dim3 grid(2, 26);
        proj26_kernel<<<grid, 256, 0, stream>>>(emb, Wih_f, bih_f, bhh_f, Wih_b, bih_b, bhh_b, proj26);
    }
    {
        dim3 grid(SEQ, 2);
        lstm_kernel<<<grid, 256, 0, stream>>>(target, proj26, Whh_f, Whh_b, hcat);
    }
    // conv as MFMA GEMM: transpose hcat -> [b][h][i] bf16; wT[(o,k)][i]; T = hcatT @ wT^T
    {
        dim3 grid(4, 32, BB); // h-tiles, i-tiles, b
        transpose_hcat<<<grid, 256, 0, stream>>>(hcat, hcatT);
    }
    reshape_convw<<<(256 * SEQ + 255) / 256, 256, 0, stream>>>(conv_w, wT);
    {
        dim3 grid(2, 64); // N=256 -> 2 tiles, M=8192 -> 64 tiles
        gemm_bf16_mfma<0><<<grid, 256, 0, stream>>>((const __hip_bfloat16*)hcatT, wT, T,
                                                    BB * 128, 256, SEQ);
    }
    conv_finalize<<<(BB * 32 * 121 + 255) / 256, 256, 0, stream>>>(T, conv_b, convout);
    transpose_f32<<<(3872 * 128 + 255) / 256, 256, 0, stream>>>(fcp_w, fcp_wt, 3872, 128);
    gemm_skinny<0><<<(BB * 128 + 3) / 4, 256, 0, stream>>>(convout, fcp_wt, fcp_b,
                                                           comb + 2 * DD, BB, 128, 3872, COMBD);

    // ---------- conversions / transposes ----------
    f32_to_bf16<<<(NN * CC + 255) / 256, 256, 0, stream>>>(x, x_bf, NN * CC);
    transpose_to_bf16<<<(CC * DD + 255) / 256, 256, 0, stream>>>(Wl, wl_t, CC, DD);
    transpose_to_bf16<<<(CC * DD + 255) / 256, 256, 0, stream>>>(Wr, wr_t, CC, DD);
    transpose_to_bf16<<<(DD * DD + 255) / 256, 256, 0, stream>>>(gcn_w, gcw_t, DD, DD);
    transpose_f32<<<(COMBD * 1024 + 255) / 256, 256, 0, stream>>>(fc1_w, fc1_wt, COMBD, 1024);
    transpose_f32<<<(1024 * 512 + 255) / 256, 256, 0, stream>>>(fc2_w, fc2_wt, 1024, 512);
    transpose_f32<<<(512 + 255) / 256, 256, 0, stream>>>(out_w, out_wt, 512, 1);

    // ---------- graph branch ----------
    dim3 ggrid((DD + 127) / 128, (NN + 127) / 128);
    gemm_bf16_mfma<1><<<ggrid, 256, 0, stream>>>(x_bf, wl_t, xl_bf, NN, DD, CC);
    gemm_bf16_mfma<1><<<ggrid, 256, 0, stream>>>(x_bf, wr_t, xr_bf, NN, DD, CC);
    // CSR
    deg_count<<<(ET + 255) / 256, 256, 0, stream>>>(ei, deg);
    scan_kernel<<<1, 1024, 0, stream>>>(deg, offs);
    csr_fill<<<(ET + 255) / 256, 256, 0, stream>>>(ei, offs, cursor, csr_src, csr_dst);
    dinv_kernel<<<(NN + 255) / 256, 256, 0, stream>>>(deg, dinv);
    // GATv2
    gat_logits<<<(ET * HH + 255) / 256, 256, 0, stream>>>((const unsigned short*)xl_bf,
                                                          (const unsigned short*)xr_bf,
                                                          att, csr_src, csr_dst, logit);
    gat_softmax<<<(NN * HH + 255) / 256, 256, 0, stream>>>(offs, logit);
    gat_aggregate<<<NN, 256, 0, stream>>>(offs, csr_src, logit,
                                          (const unsigned short*)xl_bf, gat_b, h_bf);
    // GCN: hw = h @ gcn_w^T (bf16 out, overwrites dead xl); aggregate -> g_bf (dead xr)
    gemm_bf16_mfma<1><<<ggrid, 256, 0, stream>>>(h_bf, gcw_t, hw_bf, NN, DD, DD);
    gcn_aggregate<<<NN, 256, 0, stream>>>(offs, csr_src, dinv,
                                          (const unsigned short*)hw_bf, gcn_b, g_bf);
    // pooling -> comb[:, 0:1560]
    graph_ranges<<<(NN + 255) / 256, 256, 0, stream>>>(batch, gstart, gend);
    pool_partial<<<(NN + PCHUNK - 1) / PCHUNK, 256, 0, stream>>>((const unsigned short*)g_bf,
                                                                 batch, pmax, psum);
    pool_finalize<<<(BB * DD + 255) / 256, 256, 0, stream>>>(pmax, psum, gstart, gend, comb);

    // ---------- combined head ----------
    gemm_skinny<1><<<(BB * 1024 + 3) / 4, 256, 0, stream>>>(comb, fc1_wt, fc1_b, h1,
                                                            BB, 1024, COMBD, 1024);
    gemm_skinny<1><<<(BB * 512 + 3) / 4, 256, 0, stream>>>(h1, fc2_wt, fc2_b, h2,
                                                           BB, 512, 1024, 512);
    gemm_skinny<0><<<(BB + 3) / 4, 256, 0, stream>>>(h2, out_wt, out_b, out,
                                                     BB, 1, 512, 1);
}